// Round 2
// baseline (397.348 us; speedup 1.0000x reference)
//
#include <hip/hip_runtime.h>
#include <hip/hip_bf16.h>
#include <math.h>

typedef short bf16x8 __attribute__((ext_vector_type(8)));
typedef float f32x4 __attribute__((ext_vector_type(4)));
typedef unsigned short us4 __attribute__((ext_vector_type(4)));

#define MFMA(a, b, c) __builtin_amdgcn_mfma_f32_16x16x32_bf16(a, b, c, 0, 0, 0)

__device__ __forceinline__ unsigned short f2b(float f) {
  unsigned int u = __builtin_bit_cast(unsigned int, f);
  u += 0x7fffu + ((u >> 16) & 1u);
  return (unsigned short)(u >> 16);
}

__device__ __forceinline__ void gload16(const void* g, void* l) {
  __builtin_amdgcn_global_load_lds((const unsigned int*)g, (unsigned int*)l, 16, 0, 0);
}

// ---------------- weight conversion ----------------
__global__ void cvt_k(const float* __restrict__ src, unsigned short* __restrict__ dst, int n4) {
  int i = blockIdx.x * 256 + threadIdx.x;
  if (i >= n4) return;
  float4 v = ((const float4*)src)[i];
  us4 o; o.x = f2b(v.x); o.y = f2b(v.y); o.z = f2b(v.z); o.w = f2b(v.w);
  ((us4*)dst)[i] = o;
}

__global__ void cvt_qkv_k(const float* __restrict__ wq, const float* __restrict__ wk,
                          const float* __restrict__ wv, unsigned short* __restrict__ dst) {
  int i = blockIdx.x * 256 + threadIdx.x;  // float4 index
  if (i >= 2304 * 768 / 4) return;
  int e = i * 4;
  const float* src = e < 589824 ? wq + e : (e < 1179648 ? wk + (e - 589824) : wv + (e - 1179648));
  float4 v = *(const float4*)src;
  us4 o; o.x = f2b(v.x); o.y = f2b(v.y); o.z = f2b(v.z); o.w = f2b(v.w);
  ((us4*)dst)[i] = o;
}

// ---------------- mask bias ----------------
__global__ void maskbias_k(const int* __restrict__ pm, const int* __restrict__ clp,
                           float* __restrict__ bias) {
  const int b = blockIdx.x, tid = threadIdx.x;
  int s = 0;
  for (int i = tid; i < 2048; i += 256) s += pm[b * 2048 + i];
  #pragma unroll
  for (int d = 1; d < 64; d <<= 1) s += __shfl_xor(s, d);
  __shared__ int red[4];
  if ((tid & 63) == 0) red[tid >> 6] = s;
  __syncthreads();
  const int n = 2048 - (red[0] + red[1] + red[2] + red[3]);
  const int cl = *clp;
  for (int t = tid; t < 2048; t += 256)
    bias[b * 2048 + t] = (t >= cl || t < n) ? 0.0f : -1e30f;
}

// ---------------- layernorm (f32 in -> bf16 out), one wave per row ----------------
__global__ __launch_bounds__(256)
void ln_k(const float* __restrict__ x, const float* __restrict__ g,
          const float* __restrict__ be, unsigned short* __restrict__ out) {
  const int row = blockIdx.x * 4 + (threadIdx.x >> 6);
  const int l = threadIdx.x & 63;
  const float4* xr = (const float4*)(x + (size_t)row * 768);
  float4 v[3];
  float s = 0.f, s2 = 0.f;
  #pragma unroll
  for (int j = 0; j < 3; ++j) {
    v[j] = xr[l + j * 64];
    s += v[j].x + v[j].y + v[j].z + v[j].w;
    s2 += v[j].x * v[j].x + v[j].y * v[j].y + v[j].z * v[j].z + v[j].w * v[j].w;
  }
  #pragma unroll
  for (int d = 1; d < 64; d <<= 1) { s += __shfl_xor(s, d); s2 += __shfl_xor(s2, d); }
  const float mu = s * (1.0f / 768.0f);
  const float rstd = rsqrtf(s2 * (1.0f / 768.0f) - mu * mu + 1e-5f);
  #pragma unroll
  for (int j = 0; j < 3; ++j) {
    int c0 = (l + j * 64) * 4;
    us4 ov;
    ov.x = f2b((v[j].x - mu) * rstd * g[c0 + 0] + be[c0 + 0]);
    ov.y = f2b((v[j].y - mu) * rstd * g[c0 + 1] + be[c0 + 1]);
    ov.z = f2b((v[j].z - mu) * rstd * g[c0 + 2] + be[c0 + 2]);
    ov.w = f2b((v[j].w - mu) * rstd * g[c0 + 3] + be[c0 + 3]);
    *(us4*)(out + (size_t)row * 768 + c0) = ov;
  }
}

// ---------------- GEMM: C[m][n] = sum_k A[m][k] * W[n][k] (+epilogue) ----------------
// MODE 0: QKV -> bf16 into qkv buffer (row len 2304), V-part transposed into out2
// MODE 1: f32 out = acc + bias + resid (row len N)
// MODE 2: bf16 out = gelu(acc + bias)
template<int MODE>
__global__ __launch_bounds__(256)
void gemm_k(const unsigned short* __restrict__ A, const unsigned short* __restrict__ W,
            const float* __restrict__ bias0, const float* __restrict__ bias1,
            const float* __restrict__ bias2, const float* __restrict__ resid,
            void* __restrict__ out, unsigned short* __restrict__ out2, int N, int K) {
  __shared__ __align__(16) unsigned short At[128 * 32];
  __shared__ __align__(16) unsigned short Wt[128 * 32];
  const int m0 = blockIdx.y * 128;
  const int n0 = blockIdx.x * 128;
  const int tid = threadIdx.x;
  const int w = tid >> 6, l = tid & 63;
  const int wm = w >> 1, wn = w & 1;
  const int lr = l & 15, lg = l >> 4;
  f32x4 acc[4][4] = {};

  const int nkt = K >> 5;
  for (int kt = 0; kt < nkt; ++kt) {
    const int k0 = kt << 5;
    #pragma unroll
    for (int i = 0; i < 2; ++i) {
      int slot = (i * 4 + w) * 64 + l;
      int row = slot >> 2, c8 = (slot & 3) << 3;
      gload16(A + (size_t)(m0 + row) * K + k0 + c8, (char*)At + ((i * 4 + w) * 64) * 16);
      gload16(W + (size_t)(n0 + row) * K + k0 + c8, (char*)Wt + ((i * 4 + w) * 64) * 16);
    }
    __syncthreads();
    bf16x8 af[4], bf[4];
    #pragma unroll
    for (int i = 0; i < 4; ++i) {
      af[i] = *(const bf16x8*)&At[(wm * 64 + i * 16 + lr) * 32 + lg * 8];
      bf[i] = *(const bf16x8*)&Wt[(wn * 64 + i * 16 + lr) * 32 + lg * 8];
    }
    #pragma unroll
    for (int mi = 0; mi < 4; ++mi)
      #pragma unroll
      for (int ni = 0; ni < 4; ++ni)
        acc[mi][ni] = MFMA(af[mi], bf[ni], acc[mi][ni]);
    __syncthreads();
  }

  #pragma unroll
  for (int mi = 0; mi < 4; ++mi) {
    #pragma unroll
    for (int ni = 0; ni < 4; ++ni) {
      #pragma unroll
      for (int r = 0; r < 4; ++r) {
        int row = m0 + wm * 64 + mi * 16 + lg * 4 + r;
        int col = n0 + wn * 64 + ni * 16 + lr;
        float v = acc[mi][ni][r];
        if (MODE == 0) {
          float bb = col < 768 ? bias0[col] : (col < 1536 ? bias1[col - 768] : bias2[col - 1536]);
          v += bb;
          if (col < 1536) {
            ((unsigned short*)out)[(size_t)row * 2304 + col] = f2b(v);
          } else {
            int cc = col - 1536;
            int d = cc & 63, hh = cc >> 6;
            int b = row >> 11, t = row & 2047;
            out2[(((size_t)b * 12 + hh) * 64 + d) * 2048 + t] = f2b(v);
          }
        } else if (MODE == 1) {
          v += bias0[col] + resid[(size_t)row * N + col];
          ((float*)out)[(size_t)row * N + col] = v;
        } else {
          v += bias0[col];
          v = 0.5f * v * (1.0f + erff(v * 0.70710678118f));
          ((unsigned short*)out)[(size_t)row * N + col] = f2b(v);
        }
      }
    }
  }
}

// ---------------- flash attention ----------------
// grid: (T/64, H, B), 256 threads = 4 waves, each wave owns 16 q-rows.
__global__ __launch_bounds__(256)
void attn_k(const unsigned short* __restrict__ qkv, const unsigned short* __restrict__ vt,
            const float* __restrict__ abias, unsigned short* __restrict__ y) {
  __shared__ __align__(16) unsigned short Kt[64 * 64];  // [t][d], XOR-swizzled
  __shared__ __align__(16) unsigned short Vt[64 * 64];  // [d][t], XOR-swizzled
  __shared__ __align__(16) unsigned short Pl[4][16 * 64];  // per-wave P, swizzled
  const int tile = blockIdx.x, h = blockIdx.y, b = blockIdx.z;
  const int tid = threadIdx.x, w = tid >> 6, l = tid & 63;
  const int lr = l & 15, lg = l >> 4;
  const int tq0 = tile * 64 + w * 16;

  bf16x8 qf[2];
  {
    const unsigned short* qrow = qkv + ((size_t)b * 2048 + tq0 + lr) * 2304 + h * 64;
    qf[0] = *(const bf16x8*)(qrow + lg * 8);
    qf[1] = *(const bf16x8*)(qrow + 32 + lg * 8);
  }
  f32x4 o[4] = {};
  float mrow[4] = {-1e30f, -1e30f, -1e30f, -1e30f};
  float lrow[4] = {0.f, 0.f, 0.f, 0.f};

  const unsigned short* Kg = qkv + (size_t)b * 2048 * 2304 + 768 + h * 64;
  const unsigned short* Vg = vt + ((size_t)b * 12 + h) * 64 * 2048;

  for (int kt = 0; kt < 32; ++kt) {
    const int t0 = kt * 64;
    __syncthreads();
    #pragma unroll
    for (int i = 0; i < 2; ++i) {
      int slot = (i * 4 + w) * 64 + l;
      int row = slot >> 3;
      int cc = (slot & 7) ^ (row & 7);  // pre-swizzled source -> linear LDS = swizzled layout
      gload16(Kg + (size_t)(t0 + row) * 2304 + cc * 8, (char*)Kt + ((i * 4 + w) * 64) * 16);
      gload16(Vg + (size_t)row * 2048 + t0 + cc * 8, (char*)Vt + ((i * 4 + w) * 64) * 16);
    }
    __syncthreads();

    // S = Q K^T  (rows: q via lg*4+r, cols: t via lr)
    f32x4 s[4] = {};
    #pragma unroll
    for (int kk = 0; kk < 2; ++kk)
      #pragma unroll
      for (int sub = 0; sub < 4; ++sub) {
        int trow = sub * 16 + lr;
        int boff = (trow * 128 + kk * 64 + lg * 16) ^ ((trow & 7) << 4);
        bf16x8 kf = *(const bf16x8*)((const char*)Kt + boff);
        s[sub] = MFMA(qf[kk], kf, s[sub]);
      }

    float bb[4];
    #pragma unroll
    for (int sub = 0; sub < 4; ++sub) bb[sub] = abias[b * 2048 + t0 + sub * 16 + lr];
    #pragma unroll
    for (int sub = 0; sub < 4; ++sub)
      #pragma unroll
      for (int r = 0; r < 4; ++r)
        s[sub][r] = s[sub][r] * 0.125f + bb[sub];

    float mx[4];
    #pragma unroll
    for (int r = 0; r < 4; ++r)
      mx[r] = fmaxf(fmaxf(s[0][r], s[1][r]), fmaxf(s[2][r], s[3][r]));
    #pragma unroll
    for (int d = 1; d < 16; d <<= 1)
      #pragma unroll
      for (int r = 0; r < 4; ++r)
        mx[r] = fmaxf(mx[r], __shfl_xor(mx[r], d, 16));

    float corr[4], rs[4] = {0.f, 0.f, 0.f, 0.f};
    #pragma unroll
    for (int r = 0; r < 4; ++r) {
      float mn = fmaxf(mrow[r], mx[r]);
      corr[r] = __expf(mrow[r] - mn);
      mrow[r] = mn;
    }
    #pragma unroll
    for (int sub = 0; sub < 4; ++sub)
      #pragma unroll
      for (int r = 0; r < 4; ++r) {
        float p = __expf(s[sub][r] - mrow[r]);
        s[sub][r] = p;
        rs[r] += p;
      }
    #pragma unroll
    for (int d = 1; d < 16; d <<= 1)
      #pragma unroll
      for (int r = 0; r < 4; ++r)
        rs[r] += __shfl_xor(rs[r], d, 16);
    #pragma unroll
    for (int r = 0; r < 4; ++r)
      lrow[r] = lrow[r] * corr[r] + rs[r];
    #pragma unroll
    for (int ds_ = 0; ds_ < 4; ++ds_)
      #pragma unroll
      for (int r = 0; r < 4; ++r)
        o[ds_][r] *= corr[r];

    // P (C/D layout) -> per-wave LDS (swizzled), then back as A-fragments
    #pragma unroll
    for (int sub = 0; sub < 4; ++sub)
      #pragma unroll
      for (int r = 0; r < 4; ++r) {
        int prow = lg * 4 + r;
        int boff = (prow * 128 + (sub * 16 + lr) * 2) ^ ((prow & 7) << 4);
        *(unsigned short*)((char*)Pl[w] + boff) = f2b(s[sub][r]);
      }

    #pragma unroll
    for (int kk = 0; kk < 2; ++kk) {
      int aoff = (lr * 128 + kk * 64 + lg * 16) ^ ((lr & 7) << 4);
      bf16x8 pa = *(const bf16x8*)((const char*)Pl[w] + aoff);
      #pragma unroll
      for (int ds_ = 0; ds_ < 4; ++ds_) {
        int vrow = ds_ * 16 + lr;
        int voff = (vrow * 128 + kk * 64 + lg * 16) ^ ((vrow & 7) << 4);
        bf16x8 vf = *(const bf16x8*)((const char*)Vt + voff);
        o[ds_] = MFMA(pa, vf, o[ds_]);
      }
    }
  }

  #pragma unroll
  for (int ds_ = 0; ds_ < 4; ++ds_)
    #pragma unroll
    for (int r = 0; r < 4; ++r) {
      int row = tq0 + lg * 4 + r;
      int col = ds_ * 16 + lr;
      y[((size_t)b * 2048 + row) * 768 + h * 64 + col] = f2b(o[ds_][r] / lrow[r]);
    }
}

// ---------------- host ----------------
extern "C" void kernel_launch(void* const* d_in, const int* in_sizes, int n_in,
                              void* d_out, int out_size, void* d_ws, size_t ws_size,
                              hipStream_t stream) {
  const float* x    = (const float*)d_in[0];
  const int* condp  = (const int*)d_in[1];
  const int* pmask  = (const int*)d_in[2];
  const float* g1   = (const float*)d_in[3];
  const float* bln1 = (const float*)d_in[4];
  const float* g2   = (const float*)d_in[5];
  const float* bln2 = (const float*)d_in[6];
  const float* Wq   = (const float*)d_in[7];
  const float* bq   = (const float*)d_in[8];
  const float* Wk   = (const float*)d_in[9];
  const float* bk   = (const float*)d_in[10];
  const float* Wv   = (const float*)d_in[11];
  const float* bv   = (const float*)d_in[12];
  const float* Wp   = (const float*)d_in[13];
  const float* bp   = (const float*)d_in[14];
  const float* W1   = (const float*)d_in[15];
  const float* b1   = (const float*)d_in[16];
  const float* W2   = (const float*)d_in[17];
  const float* b2   = (const float*)d_in[18];

  char* p = (char*)d_ws;
  auto alloc = [&](size_t bytes) { char* r = p; p += (bytes + 255) & ~(size_t)255; return r; };
  unsigned short* Wqkv = (unsigned short*)alloc((size_t)2304 * 768 * 2);
  unsigned short* Wpb  = (unsigned short*)alloc((size_t)589824 * 2);
  unsigned short* W1b  = (unsigned short*)alloc((size_t)2359296 * 2);
  unsigned short* W2b  = (unsigned short*)alloc((size_t)2359296 * 2);
  unsigned short* hb   = (unsigned short*)alloc((size_t)4096 * 768 * 2);
  unsigned short* qkv  = (unsigned short*)alloc((size_t)4096 * 2304 * 2);
  unsigned short* vtb  = (unsigned short*)alloc((size_t)24 * 64 * 2048 * 2);
  unsigned short* yb   = (unsigned short*)alloc((size_t)4096 * 768 * 2);
  float* xmid          = (float*)alloc((size_t)4096 * 768 * 4);
  unsigned short* h2b  = (unsigned short*)alloc((size_t)4096 * 768 * 2);
  unsigned short* mlph = (unsigned short*)alloc((size_t)4096 * 3072 * 2);
  float* abias         = (float*)alloc((size_t)2 * 2048 * 4);

  cvt_qkv_k<<<(2304 * 768 / 4 + 255) / 256, 256, 0, stream>>>(Wq, Wk, Wv, Wqkv);
  cvt_k<<<(589824 / 4 + 255) / 256, 256, 0, stream>>>(Wp, Wpb, 589824 / 4);
  cvt_k<<<(2359296 / 4 + 255) / 256, 256, 0, stream>>>(W1, W1b, 2359296 / 4);
  cvt_k<<<(2359296 / 4 + 255) / 256, 256, 0, stream>>>(W2, W2b, 2359296 / 4);
  maskbias_k<<<2, 256, 0, stream>>>(pmask, condp, abias);
  ln_k<<<1024, 256, 0, stream>>>(x, g1, bln1, hb);
  gemm_k<0><<<dim3(18, 32), 256, 0, stream>>>(hb, Wqkv, bq, bk, bv, nullptr, qkv, vtb, 2304, 768);
  attn_k<<<dim3(32, 12, 2), 256, 0, stream>>>(qkv, vtb, abias, yb);
  gemm_k<1><<<dim3(6, 32), 256, 0, stream>>>(yb, Wpb, bp, nullptr, nullptr, x, xmid, nullptr, 768, 768);
  ln_k<<<1024, 256, 0, stream>>>(xmid, g2, bln2, h2b);
  gemm_k<2><<<dim3(24, 32), 256, 0, stream>>>(h2b, W1b, b1, nullptr, nullptr, nullptr, mlph, nullptr, 3072, 768);
  gemm_k<1><<<dim3(6, 32), 256, 0, stream>>>(mlph, W2b, b2, nullptr, nullptr, xmid, (float*)d_out, nullptr, 768, 3072);
}

// Round 3
// 348.914 us; speedup vs baseline: 1.1388x; 1.1388x over previous
//
#include <hip/hip_runtime.h>
#include <hip/hip_bf16.h>
#include <math.h>

typedef short bf16x8 __attribute__((ext_vector_type(8)));
typedef float f32x4 __attribute__((ext_vector_type(4)));
typedef float f32x16 __attribute__((ext_vector_type(16)));
typedef unsigned short us4 __attribute__((ext_vector_type(4)));

#define MFMA16(a, b, c) __builtin_amdgcn_mfma_f32_16x16x32_bf16(a, b, c, 0, 0, 0)
#define MFMA32(a, b, c) __builtin_amdgcn_mfma_f32_32x32x16_bf16(a, b, c, 0, 0, 0)

__device__ __forceinline__ unsigned short f2b(float f) {
  unsigned int u = __builtin_bit_cast(unsigned int, f);
  u += 0x7fffu + ((u >> 16) & 1u);
  return (unsigned short)(u >> 16);
}

__device__ __forceinline__ float b2f(unsigned short u) {
  unsigned int x = ((unsigned int)u) << 16;
  return __builtin_bit_cast(float, x);
}

__device__ __forceinline__ unsigned int cvtpk(float lo, float hiv) {
  unsigned int r;
  asm("v_cvt_pk_bf16_f32 %0, %1, %2" : "=v"(r) : "v"(lo), "v"(hiv));
  return r;
}

__device__ __forceinline__ void gload16(const void* g, void* l) {
  __builtin_amdgcn_global_load_lds((const unsigned int*)g, (unsigned int*)l, 16, 0, 0);
}

// ---------------- weight conversion ----------------
__global__ void cvt_qkv_k(const float* __restrict__ wq, const float* __restrict__ wk,
                          const float* __restrict__ wv, unsigned short* __restrict__ dst) {
  int i = blockIdx.x * 256 + threadIdx.x;  // float4 index
  if (i >= 2304 * 768 / 4) return;
  int e = i * 4;
  const float* src = e < 589824 ? wq + e : (e < 1179648 ? wk + (e - 589824) : wv + (e - 1179648));
  float4 v = *(const float4*)src;
  us4 o; o.x = f2b(v.x); o.y = f2b(v.y); o.z = f2b(v.z); o.w = f2b(v.w);
  ((us4*)dst)[i] = o;
}

__global__ void cvt3_k(const float* __restrict__ s0, const float* __restrict__ s1,
                       const float* __restrict__ s2, unsigned short* __restrict__ d0,
                       unsigned short* __restrict__ d1, unsigned short* __restrict__ d2) {
  const int n0 = 147456, n1 = 589824, n2 = 589824;  // float4 counts
  int i = blockIdx.x * 256 + threadIdx.x;
  const float* s; unsigned short* d; int j = i;
  if (j < n0) { s = s0; d = d0; }
  else {
    j -= n0;
    if (j < n1) { s = s1; d = d1; }
    else { j -= n1; if (j >= n2) return; s = s2; d = d2; }
  }
  float4 v = ((const float4*)s)[j];
  us4 o; o.x = f2b(v.x); o.y = f2b(v.y); o.z = f2b(v.z); o.w = f2b(v.w);
  ((us4*)d)[j] = o;
}

// ---------------- mask bias ----------------
__global__ void maskbias_k(const int* __restrict__ pm, const int* __restrict__ clp,
                           float* __restrict__ bias) {
  const int b = blockIdx.x, tid = threadIdx.x;
  int s = 0;
  for (int i = tid; i < 2048; i += 256) s += pm[b * 2048 + i];
  #pragma unroll
  for (int d = 1; d < 64; d <<= 1) s += __shfl_xor(s, d);
  __shared__ int red[4];
  if ((tid & 63) == 0) red[tid >> 6] = s;
  __syncthreads();
  const int n = 2048 - (red[0] + red[1] + red[2] + red[3]);
  const int cl = *clp;
  for (int t = tid; t < 2048; t += 256)
    bias[b * 2048 + t] = (t >= cl || t < n) ? 0.0f : -1e30f;
}

// ---------------- layernorm 1 (f32 in -> bf16 out), one wave per row ----------------
__global__ __launch_bounds__(256)
void ln_k(const float* __restrict__ x, const float* __restrict__ g,
          const float* __restrict__ be, unsigned short* __restrict__ out) {
  const int row = blockIdx.x * 4 + (threadIdx.x >> 6);
  const int l = threadIdx.x & 63;
  const float4* xr = (const float4*)(x + (size_t)row * 768);
  float4 v[3];
  float s = 0.f, s2 = 0.f;
  #pragma unroll
  for (int j = 0; j < 3; ++j) {
    v[j] = xr[l + j * 64];
    s += v[j].x + v[j].y + v[j].z + v[j].w;
    s2 += v[j].x * v[j].x + v[j].y * v[j].y + v[j].z * v[j].z + v[j].w * v[j].w;
  }
  #pragma unroll
  for (int d = 1; d < 64; d <<= 1) { s += __shfl_xor(s, d); s2 += __shfl_xor(s2, d); }
  const float mu = s * (1.0f / 768.0f);
  const float rstd = rsqrtf(s2 * (1.0f / 768.0f) - mu * mu + 1e-5f);
  #pragma unroll
  for (int j = 0; j < 3; ++j) {
    int c0 = (l + j * 64) * 4;
    us4 ov;
    ov.x = f2b((v[j].x - mu) * rstd * g[c0 + 0] + be[c0 + 0]);
    ov.y = f2b((v[j].y - mu) * rstd * g[c0 + 1] + be[c0 + 1]);
    ov.z = f2b((v[j].z - mu) * rstd * g[c0 + 2] + be[c0 + 2]);
    ov.w = f2b((v[j].w - mu) * rstd * g[c0 + 3] + be[c0 + 3]);
    *(us4*)(out + (size_t)row * 768 + c0) = ov;
  }
}

// ---------------- GEMM: C[m][n] = sum_k A[m][k] * W[n][k] (+epilogue) ----------------
// MODE 0: QKV -> bf16 into qkv buffer (row len 2304), V-part transposed into out2
// MODE 2: bf16 out = gelu(acc + bias)
template<int MODE>
__global__ __launch_bounds__(256)
void gemm_k(const unsigned short* __restrict__ A, const unsigned short* __restrict__ W,
            const float* __restrict__ bias0, const float* __restrict__ bias1,
            const float* __restrict__ bias2, void* __restrict__ out,
            unsigned short* __restrict__ out2, int N, int K) {
  __shared__ __align__(16) unsigned short At[128 * 32];
  __shared__ __align__(16) unsigned short Wt[128 * 32];
  const int m0 = blockIdx.y * 128;
  const int n0 = blockIdx.x * 128;
  const int tid = threadIdx.x;
  const int w = tid >> 6, l = tid & 63;
  const int wm = w >> 1, wn = w & 1;
  const int lr = l & 15, lg = l >> 4;
  f32x4 acc[4][4] = {};

  const int nkt = K >> 5;
  for (int kt = 0; kt < nkt; ++kt) {
    const int k0 = kt << 5;
    #pragma unroll
    for (int i = 0; i < 2; ++i) {
      int slot = (i * 4 + w) * 64 + l;
      int row = slot >> 2, c8 = (slot & 3) << 3;
      gload16(A + (size_t)(m0 + row) * K + k0 + c8, (char*)At + ((i * 4 + w) * 64) * 16);
      gload16(W + (size_t)(n0 + row) * K + k0 + c8, (char*)Wt + ((i * 4 + w) * 64) * 16);
    }
    __syncthreads();
    bf16x8 af[4], bf[4];
    #pragma unroll
    for (int i = 0; i < 4; ++i) {
      af[i] = *(const bf16x8*)&At[(wm * 64 + i * 16 + lr) * 32 + lg * 8];
      bf[i] = *(const bf16x8*)&Wt[(wn * 64 + i * 16 + lr) * 32 + lg * 8];
    }
    #pragma unroll
    for (int mi = 0; mi < 4; ++mi)
      #pragma unroll
      for (int ni = 0; ni < 4; ++ni)
        acc[mi][ni] = MFMA16(af[mi], bf[ni], acc[mi][ni]);
    __syncthreads();
  }

  #pragma unroll
  for (int mi = 0; mi < 4; ++mi) {
    #pragma unroll
    for (int ni = 0; ni < 4; ++ni) {
      #pragma unroll
      for (int r = 0; r < 4; ++r) {
        int row = m0 + wm * 64 + mi * 16 + lg * 4 + r;
        int col = n0 + wn * 64 + ni * 16 + lr;
        float v = acc[mi][ni][r];
        if (MODE == 0) {
          float bb = col < 768 ? bias0[col] : (col < 1536 ? bias1[col - 768] : bias2[col - 1536]);
          v += bb;
          if (col < 1536) {
            ((unsigned short*)out)[(size_t)row * 2304 + col] = f2b(v);
          } else {
            int cc = col - 1536;
            int d = cc & 63, hh = cc >> 6;
            int b = row >> 11, t = row & 2047;
            out2[(((size_t)b * 12 + hh) * 64 + d) * 2048 + t] = f2b(v);
          }
        } else {
          v += bias0[col];
          v = 0.5f * v * (1.0f + erff(v * 0.70710678118f));
          ((unsigned short*)out)[(size_t)row * N + col] = f2b(v);
        }
      }
    }
  }
}

// ---------------- split-K GEMM -> f32 partials ----------------
__global__ __launch_bounds__(256)
void gemm_pk(const unsigned short* __restrict__ A, const unsigned short* __restrict__ W,
             float* __restrict__ part, int N, int K, int KS) {
  __shared__ __align__(16) unsigned short At[128 * 32];
  __shared__ __align__(16) unsigned short Wt[128 * 32];
  const int m0 = blockIdx.y * 128;
  const int n0 = blockIdx.x * 128;
  const int kb = blockIdx.z * KS;
  const int tid = threadIdx.x;
  const int w = tid >> 6, l = tid & 63;
  const int wm = w >> 1, wn = w & 1;
  const int lr = l & 15, lg = l >> 4;
  f32x4 acc[4][4] = {};

  const int nkt = KS >> 5;
  for (int kt = 0; kt < nkt; ++kt) {
    const int k0 = kb + (kt << 5);
    #pragma unroll
    for (int i = 0; i < 2; ++i) {
      int slot = (i * 4 + w) * 64 + l;
      int row = slot >> 2, c8 = (slot & 3) << 3;
      gload16(A + (size_t)(m0 + row) * K + k0 + c8, (char*)At + ((i * 4 + w) * 64) * 16);
      gload16(W + (size_t)(n0 + row) * K + k0 + c8, (char*)Wt + ((i * 4 + w) * 64) * 16);
    }
    __syncthreads();
    bf16x8 af[4], bf[4];
    #pragma unroll
    for (int i = 0; i < 4; ++i) {
      af[i] = *(const bf16x8*)&At[(wm * 64 + i * 16 + lr) * 32 + lg * 8];
      bf[i] = *(const bf16x8*)&Wt[(wn * 64 + i * 16 + lr) * 32 + lg * 8];
    }
    #pragma unroll
    for (int mi = 0; mi < 4; ++mi)
      #pragma unroll
      for (int ni = 0; ni < 4; ++ni)
        acc[mi][ni] = MFMA16(af[mi], bf[ni], acc[mi][ni]);
    __syncthreads();
  }

  #pragma unroll
  for (int mi = 0; mi < 4; ++mi)
    #pragma unroll
    for (int ni = 0; ni < 4; ++ni)
      #pragma unroll
      for (int r = 0; r < 4; ++r) {
        int row = m0 + wm * 64 + mi * 16 + lg * 4 + r;
        int col = n0 + wn * 64 + ni * 16 + lr;
        part[((size_t)blockIdx.z * 4096 + row) * N + col] = acc[mi][ni][r];
      }
}

// ---------------- flash attention, 8 waves x 32 q-rows, 32x32 MFMA, swapped QK^T ----------------
// grid: 768 linear blocks = (8 q-tiles) x (24 bh) x (4 kv-splits), decoded XCD-coherently.
__global__ __launch_bounds__(512, 4)
void attn_k(const unsigned short* __restrict__ qkv, const unsigned short* __restrict__ vt,
            const float* __restrict__ abias, unsigned short* __restrict__ opart,
            float* __restrict__ mpart, float* __restrict__ lpart) {
  __shared__ __align__(16) unsigned short Kt[64 * 64];  // [t][d] swizzled
  __shared__ __align__(16) unsigned short Vt[64 * 64];  // [d][t] swizzled
  __shared__ __align__(16) float absh[512];
  // decode: blocks sharing (bh,split) get same (block_id % 8) -> same XCD slot
  const int d0 = blockIdx.x;
  const int c = d0 & 7, t_ = d0 >> 3;
  const int G = (t_ >> 3) * 8 + c;      // 0..95 = bh*4 + split
  const int qt = t_ & 7;
  const int bh = G >> 2, split = G & 3;
  const int b = bh / 12, h = bh - b * 12;
  const int q0 = qt * 256;
  const int tb = split * 512;
  const int tid = threadIdx.x, w = tid >> 6, l = tid & 63;
  const int ql = l & 31, hi = l >> 5;
  const int q = q0 + w * 32 + ql;

  absh[tid] = abias[b * 2048 + tb + tid];

  // Q B-fragments: B[row=q][k=d], k = ds*16 + hi*8 + e
  bf16x8 qf[4];
  {
    const unsigned short* qrow = qkv + ((size_t)b * 2048 + q) * 2304 + h * 64 + hi * 8;
    #pragma unroll
    for (int ds = 0; ds < 4; ++ds) qf[ds] = *(const bf16x8*)(qrow + ds * 16);
  }

  f32x16 o0 = {}, o1 = {};   // o[dt] reg r: O[q = w*32 + (r&3)+8*(r>>2)+4*hi][d = dt*32 + ql]
  float mrow = -1e30f, lrow = 0.f;

  // staging addresses (pre-swizzled global source, linear LDS dest)
  const int srow = tid >> 3;
  const int scc = (tid & 7) ^ (srow & 7);
  const unsigned short* KgL = qkv + ((size_t)b * 2048 + tb + srow) * 2304 + 768 + h * 64 + scc * 8;
  const unsigned short* VgL = vt + ((size_t)bh * 64 + srow) * 2048 + tb + scc * 8;
  char* KtW = (char*)Kt + w * 1024;
  char* VtW = (char*)Vt + w * 1024;

  for (int tt = 0; tt < 8; ++tt) {
    gload16(KgL + (size_t)(tt * 64) * 2304, KtW);
    gload16(VgL + tt * 64, VtW);
    __syncthreads();

    // S^T = K·Q^T: lane holds S[q=ql][t = st*32 + (r&3)+8*(r>>2)+4*hi]
    f32x16 sa0 = {}, sa1 = {};
    {
      const int r0 = ql, r1 = 32 + ql;
      #pragma unroll
      for (int ds = 0; ds < 4; ++ds) {
        bf16x8 kf0 = *(const bf16x8*)((const char*)Kt + r0 * 128 + (((ds * 2 + hi) ^ (r0 & 7)) << 4));
        bf16x8 kf1 = *(const bf16x8*)((const char*)Kt + r1 * 128 + (((ds * 2 + hi) ^ (r1 & 7)) << 4));
        sa0 = MFMA32(kf0, qf[ds], sa0);
        sa1 = MFMA32(kf1, qf[ds], sa1);
      }
    }

    // scale + mask-bias + tile max
    float mt = -1e30f;
    #pragma unroll
    for (int g = 0; g < 4; ++g) {
      float4 b0 = *(const float4*)&absh[tt * 64 + g * 8 + hi * 4];
      float4 b1 = *(const float4*)&absh[tt * 64 + 32 + g * 8 + hi * 4];
      float bb0[4] = {b0.x, b0.y, b0.z, b0.w};
      float bb1[4] = {b1.x, b1.y, b1.z, b1.w};
      #pragma unroll
      for (int r2 = 0; r2 < 4; ++r2) {
        float v0 = sa0[g * 4 + r2] * 0.125f + bb0[r2];
        float v1 = sa1[g * 4 + r2] * 0.125f + bb1[r2];
        sa0[g * 4 + r2] = v0; sa1[g * 4 + r2] = v1;
        mt = fmaxf(mt, fmaxf(v0, v1));
      }
    }
    mt = fmaxf(mt, __shfl_xor(mt, 32));

    const bool grow = mt > mrow;
    const float mnew = grow ? mt : mrow;
    const float corr = __expf(mrow - mnew);
    mrow = mnew;
    if (__any((int)grow)) {
      // broadcast corr (owned by lane q) to o-layout rows, rescale o
      #pragma unroll
      for (int g = 0; g < 4; ++g)
        #pragma unroll
        for (int r2 = 0; r2 < 4; ++r2) {
          float cc2 = __shfl(corr, g * 8 + hi * 4 + r2);
          o0[g * 4 + r2] *= cc2;
          o1[g * 4 + r2] *= cc2;
        }
    }

    float rs = 0.f;
    // exp + pack P into A-fragments + PV, one 32-t half at a time
    auto half_pv = [&](const f32x16& sv, int ksb) {
      unsigned int u[8];
      #pragma unroll
      for (int g = 0; g < 4; ++g) {
        float e0 = __expf(sv[g * 4 + 0] - mnew);
        float e1 = __expf(sv[g * 4 + 1] - mnew);
        float e2 = __expf(sv[g * 4 + 2] - mnew);
        float e3 = __expf(sv[g * 4 + 3] - mnew);
        rs += (e0 + e1) + (e2 + e3);
        u[g * 2]     = cvtpk(e0, e1);
        u[g * 2 + 1] = cvtpk(e2, e3);
      }
      #pragma unroll
      for (int kh = 0; kh < 2; ++kh) {
        unsigned int a0 = u[kh * 4 + 0], a1 = u[kh * 4 + 1];
        unsigned int c0 = u[kh * 4 + 2], c1 = u[kh * 4 + 3];
        unsigned int xa0 = (unsigned int)__shfl_xor((int)a0, 32);
        unsigned int xa1 = (unsigned int)__shfl_xor((int)a1, 32);
        unsigned int xc0 = (unsigned int)__shfl_xor((int)c0, 32);
        unsigned int xc1 = (unsigned int)__shfl_xor((int)c1, 32);
        uint4 pk;
        pk.x = hi ? xc0 : a0;
        pk.y = hi ? xc1 : a1;
        pk.z = hi ? c0 : xa0;
        pk.w = hi ? c1 : xa1;
        bf16x8 pa = __builtin_bit_cast(bf16x8, pk);
        const int ks = ksb + kh;
        const int vr0 = ql, vr1 = 32 + ql;
        bf16x8 vf0 = *(const bf16x8*)((const char*)Vt + vr0 * 128 + (((ks * 2 + hi) ^ (vr0 & 7)) << 4));
        o0 = MFMA32(pa, vf0, o0);
        bf16x8 vf1 = *(const bf16x8*)((const char*)Vt + vr1 * 128 + (((ks * 2 + hi) ^ (vr1 & 7)) << 4));
        o1 = MFMA32(pa, vf1, o1);
      }
    };
    half_pv(sa0, 0);
    half_pv(sa1, 2);

    rs += __shfl_xor(rs, 32);
    lrow = lrow * corr + rs;
    __syncthreads();
  }

  const size_t orow0 = (size_t)split * 49152 + (size_t)bh * 2048 + q0 + w * 32;
  if (hi == 0) { mpart[orow0 + ql] = mrow; lpart[orow0 + ql] = lrow; }
  #pragma unroll
  for (int g = 0; g < 4; ++g)
    #pragma unroll
    for (int r2 = 0; r2 < 4; ++r2) {
      int oq = r2 + g * 8 + hi * 4;
      opart[(orow0 + oq) * 64 + ql]      = f2b(o0[g * 4 + r2]);
      opart[(orow0 + oq) * 64 + 32 + ql] = f2b(o1[g * 4 + r2]);
    }
}

// ---------------- attention split combine ----------------
__global__ __launch_bounds__(256)
void attn_comb_k(const unsigned short* __restrict__ op, const float* __restrict__ mp,
                 const float* __restrict__ lp, unsigned short* __restrict__ y) {
  const int row = blockIdx.x * 4 + (threadIdx.x >> 6);
  const int l = threadIdx.x & 63;
  float m0 = mp[row], m1 = mp[49152 + row], m2 = mp[2 * 49152 + row], m3 = mp[3 * 49152 + row];
  float M = fmaxf(fmaxf(m0, m1), fmaxf(m2, m3));
  float w0 = __expf(m0 - M), w1 = __expf(m1 - M), w2 = __expf(m2 - M), w3 = __expf(m3 - M);
  float den = w0 * lp[row] + w1 * lp[49152 + row] + w2 * lp[2 * 49152 + row] + w3 * lp[3 * 49152 + row];
  float num = w0 * b2f(op[((size_t)0 * 49152 + row) * 64 + l])
            + w1 * b2f(op[((size_t)1 * 49152 + row) * 64 + l])
            + w2 * b2f(op[((size_t)2 * 49152 + row) * 64 + l])
            + w3 * b2f(op[((size_t)3 * 49152 + row) * 64 + l]);
  const int bh = row >> 11, qq = row & 2047;
  const int bb = bh / 12, hh = bh - bb * 12;
  y[((size_t)(bb * 2048 + qq)) * 768 + hh * 64 + l] = f2b(num / den);
}

// ---------------- proj combine + residual + LN2 fused ----------------
__global__ __launch_bounds__(256)
void proj_ln_k(const float* __restrict__ part, const float* __restrict__ bp,
               const float* __restrict__ xres, const float* __restrict__ g2,
               const float* __restrict__ bln2, float* __restrict__ xmid,
               unsigned short* __restrict__ h2) {
  const int row = blockIdx.x * 4 + (threadIdx.x >> 6);
  const int l = threadIdx.x & 63;
  float4 v[3];
  float s = 0.f, s2 = 0.f;
  #pragma unroll
  for (int j = 0; j < 3; ++j) {
    const int cc = l + j * 64;
    float4 a = ((const float4*)(xres + (size_t)row * 768))[cc];
    float4 bb = ((const float4*)bp)[cc];
    a.x += bb.x; a.y += bb.y; a.z += bb.z; a.w += bb.w;
    #pragma unroll
    for (int sp = 0; sp < 4; ++sp) {
      float4 pp = ((const float4*)(part + ((size_t)sp * 4096 + row) * 768))[cc];
      a.x += pp.x; a.y += pp.y; a.z += pp.z; a.w += pp.w;
    }
    v[j] = a;
    s += a.x + a.y + a.z + a.w;
    s2 += a.x * a.x + a.y * a.y + a.z * a.z + a.w * a.w;
  }
  #pragma unroll
  for (int d = 1; d < 64; d <<= 1) { s += __shfl_xor(s, d); s2 += __shfl_xor(s2, d); }
  const float mu = s * (1.0f / 768.0f);
  const float rstd = rsqrtf(s2 * (1.0f / 768.0f) - mu * mu + 1e-5f);
  #pragma unroll
  for (int j = 0; j < 3; ++j) {
    const int cc = l + j * 64;
    ((float4*)(xmid + (size_t)row * 768))[cc] = v[j];
    const int c0 = cc * 4;
    us4 ov;
    ov.x = f2b((v[j].x - mu) * rstd * g2[c0 + 0] + bln2[c0 + 0]);
    ov.y = f2b((v[j].y - mu) * rstd * g2[c0 + 1] + bln2[c0 + 1]);
    ov.z = f2b((v[j].z - mu) * rstd * g2[c0 + 2] + bln2[c0 + 2]);
    ov.w = f2b((v[j].w - mu) * rstd * g2[c0 + 3] + bln2[c0 + 3]);
    *(us4*)(h2 + (size_t)row * 768 + c0) = ov;
  }
}

// ---------------- MLP2 combine + bias + residual -> f32 out ----------------
__global__ void mlp2_comb_k(const float* __restrict__ part, const float* __restrict__ b2,
                            const float* __restrict__ xmid, float* __restrict__ out) {
  const int i = blockIdx.x * 256 + threadIdx.x;  // float4 index
  if (i >= 786432) return;
  const int c4 = i % 192;
  float4 a = ((const float4*)xmid)[i];
  float4 bb = ((const float4*)b2)[c4];
  a.x += bb.x; a.y += bb.y; a.z += bb.z; a.w += bb.w;
  #pragma unroll
  for (int sp = 0; sp < 4; ++sp) {
    float4 pp = ((const float4*)part)[(size_t)sp * 786432 + i];
    a.x += pp.x; a.y += pp.y; a.z += pp.z; a.w += pp.w;
  }
  ((float4*)out)[i] = a;
}

// ---------------- host ----------------
extern "C" void kernel_launch(void* const* d_in, const int* in_sizes, int n_in,
                              void* d_out, int out_size, void* d_ws, size_t ws_size,
                              hipStream_t stream) {
  const float* x    = (const float*)d_in[0];
  const int* condp  = (const int*)d_in[1];
  const int* pmask  = (const int*)d_in[2];
  const float* g1   = (const float*)d_in[3];
  const float* bln1 = (const float*)d_in[4];
  const float* g2   = (const float*)d_in[5];
  const float* bln2 = (const float*)d_in[6];
  const float* Wq   = (const float*)d_in[7];
  const float* bq   = (const float*)d_in[8];
  const float* Wk   = (const float*)d_in[9];
  const float* bk   = (const float*)d_in[10];
  const float* Wv   = (const float*)d_in[11];
  const float* bv   = (const float*)d_in[12];
  const float* Wp   = (const float*)d_in[13];
  const float* bp   = (const float*)d_in[14];
  const float* W1   = (const float*)d_in[15];
  const float* b1   = (const float*)d_in[16];
  const float* W2   = (const float*)d_in[17];
  const float* b2   = (const float*)d_in[18];

  char* p = (char*)d_ws;
  auto alloc = [&](size_t bytes) { char* r = p; p += (bytes + 255) & ~(size_t)255; return r; };
  unsigned short* Wqkv = (unsigned short*)alloc((size_t)2304 * 768 * 2);
  unsigned short* Wpb  = (unsigned short*)alloc((size_t)589824 * 2);
  unsigned short* W1b  = (unsigned short*)alloc((size_t)2359296 * 2);
  unsigned short* W2b  = (unsigned short*)alloc((size_t)2359296 * 2);
  unsigned short* hb   = (unsigned short*)alloc((size_t)4096 * 768 * 2);
  unsigned short* qkv  = (unsigned short*)alloc((size_t)4096 * 2304 * 2);
  unsigned short* vtb  = (unsigned short*)alloc((size_t)24 * 64 * 2048 * 2);
  float* xmid          = (float*)alloc((size_t)4096 * 768 * 4);
  unsigned short* h2b  = (unsigned short*)alloc((size_t)4096 * 768 * 2);
  float* abias         = (float*)alloc((size_t)2 * 2048 * 4);
  float* partial       = (float*)alloc((size_t)4 * 4096 * 768 * 4);   // 50.3 MB, multi-use
  // aliases (lifetimes disjoint):
  unsigned short* yb   = hb;                       // y after attn; hb dead after QKV gemm
  unsigned short* mlph = qkv;                      // spans qkv+vtb (25.17 MB), dead after attn
  unsigned short* opart = (unsigned short*)partial;                       // 25.17 MB
  float* mpart = (float*)((char*)partial + (size_t)4 * 49152 * 64 * 2);   // 786 KB
  float* lpart = mpart + 4 * 49152;                                       // 786 KB

  cvt_qkv_k<<<1728, 256, 0, stream>>>(Wq, Wk, Wv, Wqkv);
  cvt3_k<<<5184, 256, 0, stream>>>(Wp, W1, W2, Wpb, W1b, W2b);
  maskbias_k<<<2, 256, 0, stream>>>(pmask, condp, abias);
  ln_k<<<1024, 256, 0, stream>>>(x, g1, bln1, hb);
  gemm_k<0><<<dim3(18, 32), 256, 0, stream>>>(hb, Wqkv, bq, bk, bv, qkv, vtb, 2304, 768);
  attn_k<<<768, 512, 0, stream>>>(qkv, vtb, abias, opart, mpart, lpart);
  attn_comb_k<<<12288, 256, 0, stream>>>(opart, mpart, lpart, yb);
  gemm_pk<<<dim3(6, 32, 4), 256, 0, stream>>>(yb, Wpb, partial, 768, 768, 192);
  proj_ln_k<<<1024, 256, 0, stream>>>(partial, bp, x, g2, bln2, xmid, h2b);
  gemm_k<2><<<dim3(24, 32), 256, 0, stream>>>(h2b, W1b, b1, nullptr, nullptr, mlph, nullptr, 3072, 768);
  gemm_pk<<<dim3(6, 32, 4), 256, 0, stream>>>(mlph, W2b, partial, 768, 3072, 768);
  mlp2_comb_k<<<3072, 256, 0, stream>>>(partial, b2, xmid, (float*)d_out);
}

// Round 5
// 343.611 us; speedup vs baseline: 1.1564x; 1.0154x over previous
//
#include <hip/hip_runtime.h>
#include <hip/hip_bf16.h>
#include <math.h>

typedef short bf16x8 __attribute__((ext_vector_type(8)));
typedef float f32x4 __attribute__((ext_vector_type(4)));
typedef float f32x16 __attribute__((ext_vector_type(16)));
typedef unsigned short us4 __attribute__((ext_vector_type(4)));

#define MFMA16(a, b, c) __builtin_amdgcn_mfma_f32_16x16x32_bf16(a, b, c, 0, 0, 0)
#define MFMA32(a, b, c) __builtin_amdgcn_mfma_f32_32x32x16_bf16(a, b, c, 0, 0, 0)

__device__ __forceinline__ unsigned short f2b(float f) {
  unsigned int u = __builtin_bit_cast(unsigned int, f);
  u += 0x7fffu + ((u >> 16) & 1u);
  return (unsigned short)(u >> 16);
}

__device__ __forceinline__ float b2f(unsigned short u) {
  unsigned int x = ((unsigned int)u) << 16;
  return __builtin_bit_cast(float, x);
}

__device__ __forceinline__ unsigned int cvtpk(float lo, float hiv) {
  unsigned int r;
  asm("v_cvt_pk_bf16_f32 %0, %1, %2" : "=v"(r) : "v"(lo), "v"(hiv));
  return r;
}

__device__ __forceinline__ void gload16(const void* g, void* l) {
  __builtin_amdgcn_global_load_lds((const unsigned int*)g, (unsigned int*)l, 16, 0, 0);
}

// ---------------- weight conversion ----------------
__global__ void cvt_qkv_k(const float* __restrict__ wq, const float* __restrict__ wk,
                          const float* __restrict__ wv, unsigned short* __restrict__ dst) {
  int i = blockIdx.x * 256 + threadIdx.x;  // float4 index
  if (i >= 2304 * 768 / 4) return;
  int e = i * 4;
  const float* src = e < 589824 ? wq + e : (e < 1179648 ? wk + (e - 589824) : wv + (e - 1179648));
  float4 v = *(const float4*)src;
  us4 o; o.x = f2b(v.x); o.y = f2b(v.y); o.z = f2b(v.z); o.w = f2b(v.w);
  ((us4*)dst)[i] = o;
}

__global__ void cvt3_k(const float* __restrict__ s0, const float* __restrict__ s1,
                       const float* __restrict__ s2, unsigned short* __restrict__ d0,
                       unsigned short* __restrict__ d1, unsigned short* __restrict__ d2) {
  const int n0 = 147456, n1 = 589824, n2 = 589824;  // float4 counts
  int i = blockIdx.x * 256 + threadIdx.x;
  const float* s; unsigned short* d; int j = i;
  if (j < n0) { s = s0; d = d0; }
  else {
    j -= n0;
    if (j < n1) { s = s1; d = d1; }
    else { j -= n1; if (j >= n2) return; s = s2; d = d2; }
  }
  float4 v = ((const float4*)s)[j];
  us4 o; o.x = f2b(v.x); o.y = f2b(v.y); o.z = f2b(v.z); o.w = f2b(v.w);
  ((us4*)d)[j] = o;
}

// ---------------- mask bias ----------------
__global__ void maskbias_k(const int* __restrict__ pm, const int* __restrict__ clp,
                           float* __restrict__ bias) {
  const int b = blockIdx.x, tid = threadIdx.x;
  int s = 0;
  for (int i = tid; i < 2048; i += 256) s += pm[b * 2048 + i];
  #pragma unroll
  for (int d = 1; d < 64; d <<= 1) s += __shfl_xor(s, d);
  __shared__ int red[4];
  if ((tid & 63) == 0) red[tid >> 6] = s;
  __syncthreads();
  const int n = 2048 - (red[0] + red[1] + red[2] + red[3]);
  const int cl = *clp;
  for (int t = tid; t < 2048; t += 256)
    bias[b * 2048 + t] = (t >= cl || t < n) ? 0.0f : -1e30f;
}

// ---------------- layernorm 1 (f32 in -> bf16 out), one wave per row ----------------
__global__ __launch_bounds__(256)
void ln_k(const float* __restrict__ x, const float* __restrict__ g,
          const float* __restrict__ be, unsigned short* __restrict__ out) {
  const int row = blockIdx.x * 4 + (threadIdx.x >> 6);
  const int l = threadIdx.x & 63;
  const float4* xr = (const float4*)(x + (size_t)row * 768);
  float4 v[3];
  float s = 0.f, s2 = 0.f;
  #pragma unroll
  for (int j = 0; j < 3; ++j) {
    v[j] = xr[l + j * 64];
    s += v[j].x + v[j].y + v[j].z + v[j].w;
    s2 += v[j].x * v[j].x + v[j].y * v[j].y + v[j].z * v[j].z + v[j].w * v[j].w;
  }
  #pragma unroll
  for (int d = 1; d < 64; d <<= 1) { s += __shfl_xor(s, d); s2 += __shfl_xor(s2, d); }
  const float mu = s * (1.0f / 768.0f);
  const float rstd = rsqrtf(s2 * (1.0f / 768.0f) - mu * mu + 1e-5f);
  #pragma unroll
  for (int j = 0; j < 3; ++j) {
    int c0 = (l + j * 64) * 4;
    us4 ov;
    ov.x = f2b((v[j].x - mu) * rstd * g[c0 + 0] + be[c0 + 0]);
    ov.y = f2b((v[j].y - mu) * rstd * g[c0 + 1] + be[c0 + 1]);
    ov.z = f2b((v[j].z - mu) * rstd * g[c0 + 2] + be[c0 + 2]);
    ov.w = f2b((v[j].w - mu) * rstd * g[c0 + 3] + be[c0 + 3]);
    *(us4*)(out + (size_t)row * 768 + c0) = ov;
  }
}

// ======== pipelined GEMM core: BK=64, double-buffered LDS, XOR-swizzled ========
// LDS tile [128][64] bf16, 128B rows, chunk(16B) swizzle: c ^= row&7.
// Stage: 4 gload16 per thread per matrix (1024 slots), inverse-swizzled source.
#define GEMM_STAGE(buf, k0)                                                        \
  {                                                                                \
    _Pragma("unroll")                                                              \
    for (int i = 0; i < 4; ++i) {                                                  \
      int slot = i * 256 + tid;                                                    \
      int row = slot >> 3;                                                         \
      int c = (slot & 7) ^ (row & 7);                                              \
      gload16(A + (size_t)(m0 + row) * K + (k0) + c * 8,                           \
              (char*)At[buf] + slot * 16);                                         \
      gload16(W + (size_t)(n0 + row) * K + (k0) + c * 8,                           \
              (char*)Wt[buf] + slot * 16);                                         \
    }                                                                              \
  }

#define GEMM_COMPUTE(buf)                                                          \
  {                                                                                \
    const char* Ab = (const char*)At[buf];                                         \
    const char* Wb = (const char*)Wt[buf];                                         \
    _Pragma("unroll")                                                              \
    for (int kk = 0; kk < 2; ++kk) {                                               \
      bf16x8 af[4], bfr[4];                                                        \
      _Pragma("unroll")                                                            \
      for (int i = 0; i < 4; ++i) {                                                \
        int ar = wm * 64 + i * 16 + lr;                                            \
        af[i] = *(const bf16x8*)(Ab + ar * 128 + (((kk * 4 + lg) ^ (ar & 7)) << 4));\
        int br = wn * 64 + i * 16 + lr;                                            \
        bfr[i] = *(const bf16x8*)(Wb + br * 128 + (((kk * 4 + lg) ^ (br & 7)) << 4));\
      }                                                                            \
      _Pragma("unroll")                                                            \
      for (int mi = 0; mi < 4; ++mi)                                               \
        _Pragma("unroll")                                                          \
        for (int ni = 0; ni < 4; ++ni)                                             \
          acc[mi][ni] = MFMA16(af[mi], bfr[ni], acc[mi][ni]);                      \
    }                                                                              \
  }

// ---------------- GEMM: C[m][n] = sum_k A[m][k] * W[n][k] (+epilogue) ----------------
// MODE 0: QKV -> bf16 into qkv buffer (row len 2304), V-part transposed into out2
// MODE 2: bf16 out = gelu(acc + bias)
// 1D grid, XCD-chunked: swz = (id&7)*(nwg/8) + id/8; m fastest (NM=32 fixed).
template<int MODE>
__global__ __launch_bounds__(256)
void gemm_k(const unsigned short* __restrict__ A, const unsigned short* __restrict__ W,
            const float* __restrict__ bias0, const float* __restrict__ bias1,
            const float* __restrict__ bias2, void* __restrict__ out,
            unsigned short* __restrict__ out2, int N, int K, int NN) {
  __shared__ __align__(16) unsigned short At[2][128 * 64];
  __shared__ __align__(16) unsigned short Wt[2][128 * 64];
  const int nwg8 = gridDim.x >> 3;
  const int swz = (blockIdx.x & 7) * nwg8 + (blockIdx.x >> 3);
  const int m0 = (swz & 31) * 128;
  const int n0 = ((swz >> 5) % NN) * 128;
  const int tid = threadIdx.x;
  const int w = tid >> 6, l = tid & 63;
  const int wm = w >> 1, wn = w & 1;
  const int lr = l & 15, lg = l >> 4;
  f32x4 acc[4][4] = {};

  const int nkt = K >> 6;
  GEMM_STAGE(0, 0);
  __syncthreads();
  for (int kt = 0; kt < nkt; ++kt) {
    if (kt + 1 < nkt) GEMM_STAGE((kt + 1) & 1, (kt + 1) << 6);
    GEMM_COMPUTE(kt & 1);
    __syncthreads();
  }

  #pragma unroll
  for (int mi = 0; mi < 4; ++mi) {
    #pragma unroll
    for (int ni = 0; ni < 4; ++ni) {
      #pragma unroll
      for (int r = 0; r < 4; ++r) {
        int row = m0 + wm * 64 + mi * 16 + lg * 4 + r;
        int col = n0 + wn * 64 + ni * 16 + lr;
        float v = acc[mi][ni][r];
        if (MODE == 0) {
          float bb = col < 768 ? bias0[col] : (col < 1536 ? bias1[col - 768] : bias2[col - 1536]);
          v += bb;
          if (col < 1536) {
            ((unsigned short*)out)[(size_t)row * 2304 + col] = f2b(v);
          } else {
            int cc = col - 1536;
            int d = cc & 63, hh = cc >> 6;
            int b = row >> 11, t = row & 2047;
            out2[(((size_t)b * 12 + hh) * 64 + d) * 2048 + t] = f2b(v);
          }
        } else {
          v += bias0[col];
          v = 0.5f * v * (1.0f + erff(v * 0.70710678118f));
          ((unsigned short*)out)[(size_t)row * N + col] = f2b(v);
        }
      }
    }
  }
}

// ---------------- split-K GEMM -> f32 partials (same pipelined core) ----------------
__global__ __launch_bounds__(256)
void gemm_pk(const unsigned short* __restrict__ A, const unsigned short* __restrict__ W,
             float* __restrict__ part, int N, int K, int KS, int NN) {
  __shared__ __align__(16) unsigned short At[2][128 * 64];
  __shared__ __align__(16) unsigned short Wt[2][128 * 64];
  const int nwg8 = gridDim.x >> 3;
  const int swz = (blockIdx.x & 7) * nwg8 + (blockIdx.x >> 3);
  const int m0 = (swz & 31) * 128;
  const int rest = swz >> 5;
  const int n0 = (rest % NN) * 128;
  const int kb = (rest / NN) * KS;
  const int tid = threadIdx.x;
  const int w = tid >> 6, l = tid & 63;
  const int wm = w >> 1, wn = w & 1;
  const int lr = l & 15, lg = l >> 4;
  f32x4 acc[4][4] = {};

  const int nkt = KS >> 6;
  GEMM_STAGE(0, kb);
  __syncthreads();
  for (int kt = 0; kt < nkt; ++kt) {
    if (kt + 1 < nkt) GEMM_STAGE((kt + 1) & 1, kb + ((kt + 1) << 6));
    GEMM_COMPUTE(kt & 1);
    __syncthreads();
  }

  #pragma unroll
  for (int mi = 0; mi < 4; ++mi)
    #pragma unroll
    for (int ni = 0; ni < 4; ++ni)
      #pragma unroll
      for (int r = 0; r < 4; ++r) {
        int row = m0 + wm * 64 + mi * 16 + lg * 4 + r;
        int col = n0 + wn * 64 + ni * 16 + lr;
        part[((size_t)(rest / NN) * 4096 + row) * N + col] = acc[mi][ni][r];
      }
}

// ---------------- flash attention, 8 waves x 32 q-rows, 32x32 MFMA, swapped QK^T ----------------
// grid: 768 linear blocks = (8 q-tiles) x (24 bh) x (4 kv-splits), decoded XCD-coherently.
__global__ __launch_bounds__(512, 4)
void attn_k(const unsigned short* __restrict__ qkv, const unsigned short* __restrict__ vt,
            const float* __restrict__ abias, unsigned short* __restrict__ opart,
            float* __restrict__ mpart, float* __restrict__ lpart) {
  __shared__ __align__(16) unsigned short Kt[64 * 64];  // [t][d] swizzled
  __shared__ __align__(16) unsigned short Vt[64 * 64];  // [d][t] swizzled
  __shared__ __align__(16) float absh[512];
  const int d0 = blockIdx.x;
  const int c = d0 & 7, t_ = d0 >> 3;
  const int G = (t_ >> 3) * 8 + c;      // 0..95 = bh*4 + split
  const int qt = t_ & 7;
  const int bh = G >> 2, split = G & 3;
  const int b = bh / 12, h = bh - b * 12;
  const int q0 = qt * 256;
  const int tb = split * 512;
  const int tid = threadIdx.x, w = tid >> 6, l = tid & 63;
  const int ql = l & 31, hi = l >> 5;
  const int q = q0 + w * 32 + ql;

  absh[tid] = abias[b * 2048 + tb + tid];

  bf16x8 qf[4];
  {
    const unsigned short* qrow = qkv + ((size_t)b * 2048 + q) * 2304 + h * 64 + hi * 8;
    #pragma unroll
    for (int ds = 0; ds < 4; ++ds) qf[ds] = *(const bf16x8*)(qrow + ds * 16);
  }

  f32x16 o0 = {}, o1 = {};
  float mrow = -1e30f, lrow = 0.f;

  const int srow = tid >> 3;
  const int scc = (tid & 7) ^ (srow & 7);
  const unsigned short* KgL = qkv + ((size_t)b * 2048 + tb + srow) * 2304 + 768 + h * 64 + scc * 8;
  const unsigned short* VgL = vt + ((size_t)bh * 64 + srow) * 2048 + tb + scc * 8;
  char* KtW = (char*)Kt + w * 1024;
  char* VtW = (char*)Vt + w * 1024;

  for (int tt = 0; tt < 8; ++tt) {
    gload16(KgL + (size_t)(tt * 64) * 2304, KtW);
    gload16(VgL + tt * 64, VtW);
    __syncthreads();

    f32x16 sa0 = {}, sa1 = {};
    {
      const int r0 = ql, r1 = 32 + ql;
      #pragma unroll
      for (int ds = 0; ds < 4; ++ds) {
        bf16x8 kf0 = *(const bf16x8*)((const char*)Kt + r0 * 128 + (((ds * 2 + hi) ^ (r0 & 7)) << 4));
        bf16x8 kf1 = *(const bf16x8*)((const char*)Kt + r1 * 128 + (((ds * 2 + hi) ^ (r1 & 7)) << 4));
        sa0 = MFMA32(kf0, qf[ds], sa0);
        sa1 = MFMA32(kf1, qf[ds], sa1);
      }
    }

    float mt = -1e30f;
    #pragma unroll
    for (int g = 0; g < 4; ++g) {
      float4 b0 = *(const float4*)&absh[tt * 64 + g * 8 + hi * 4];
      float4 b1 = *(const float4*)&absh[tt * 64 + 32 + g * 8 + hi * 4];
      float bb0[4] = {b0.x, b0.y, b0.z, b0.w};
      float bb1[4] = {b1.x, b1.y, b1.z, b1.w};
      #pragma unroll
      for (int r2 = 0; r2 < 4; ++r2) {
        float v0 = sa0[g * 4 + r2] * 0.125f + bb0[r2];
        float v1 = sa1[g * 4 + r2] * 0.125f + bb1[r2];
        sa0[g * 4 + r2] = v0; sa1[g * 4 + r2] = v1;
        mt = fmaxf(mt, fmaxf(v0, v1));
      }
    }
    mt = fmaxf(mt, __shfl_xor(mt, 32));

    const bool grow = mt > mrow;
    const float mnew = grow ? mt : mrow;
    const float corr = __expf(mrow - mnew);
    mrow = mnew;
    if (__any((int)grow)) {
      #pragma unroll
      for (int g = 0; g < 4; ++g)
        #pragma unroll
        for (int r2 = 0; r2 < 4; ++r2) {
          float cc2 = __shfl(corr, g * 8 + hi * 4 + r2);
          o0[g * 4 + r2] *= cc2;
          o1[g * 4 + r2] *= cc2;
        }
    }

    float rs = 0.f;
    auto half_pv = [&](const f32x16& sv, int ksb) {
      unsigned int u[8];
      #pragma unroll
      for (int g = 0; g < 4; ++g) {
        float e0 = __expf(sv[g * 4 + 0] - mnew);
        float e1 = __expf(sv[g * 4 + 1] - mnew);
        float e2 = __expf(sv[g * 4 + 2] - mnew);
        float e3 = __expf(sv[g * 4 + 3] - mnew);
        rs += (e0 + e1) + (e2 + e3);
        u[g * 2]     = cvtpk(e0, e1);
        u[g * 2 + 1] = cvtpk(e2, e3);
      }
      #pragma unroll
      for (int kh = 0; kh < 2; ++kh) {
        unsigned int a0 = u[kh * 4 + 0], a1 = u[kh * 4 + 1];
        unsigned int c0 = u[kh * 4 + 2], c1 = u[kh * 4 + 3];
        unsigned int xa0 = (unsigned int)__shfl_xor((int)a0, 32);
        unsigned int xa1 = (unsigned int)__shfl_xor((int)a1, 32);
        unsigned int xc0 = (unsigned int)__shfl_xor((int)c0, 32);
        unsigned int xc1 = (unsigned int)__shfl_xor((int)c1, 32);
        uint4 pk;
        pk.x = hi ? xc0 : a0;
        pk.y = hi ? xc1 : a1;
        pk.z = hi ? c0 : xa0;
        pk.w = hi ? c1 : xa1;
        bf16x8 pa = __builtin_bit_cast(bf16x8, pk);
        const int ks = ksb + kh;
        const int vr0 = ql, vr1 = 32 + ql;
        bf16x8 vf0 = *(const bf16x8*)((const char*)Vt + vr0 * 128 + (((ks * 2 + hi) ^ (vr0 & 7)) << 4));
        o0 = MFMA32(pa, vf0, o0);
        bf16x8 vf1 = *(const bf16x8*)((const char*)Vt + vr1 * 128 + (((ks * 2 + hi) ^ (vr1 & 7)) << 4));
        o1 = MFMA32(pa, vf1, o1);
      }
    };
    half_pv(sa0, 0);
    half_pv(sa1, 2);

    rs += __shfl_xor(rs, 32);
    lrow = lrow * corr + rs;
    __syncthreads();
  }

  const size_t orow0 = (size_t)split * 49152 + (size_t)bh * 2048 + q0 + w * 32;
  if (hi == 0) { mpart[orow0 + ql] = mrow; lpart[orow0 + ql] = lrow; }
  #pragma unroll
  for (int g = 0; g < 4; ++g)
    #pragma unroll
    for (int r2 = 0; r2 < 4; ++r2) {
      int oq = r2 + g * 8 + hi * 4;
      opart[(orow0 + oq) * 64 + ql]      = f2b(o0[g * 4 + r2]);
      opart[(orow0 + oq) * 64 + 32 + ql] = f2b(o1[g * 4 + r2]);
    }
}

// ---------------- attention split combine ----------------
__global__ __launch_bounds__(256)
void attn_comb_k(const unsigned short* __restrict__ op, const float* __restrict__ mp,
                 const float* __restrict__ lp, unsigned short* __restrict__ y) {
  const int row = blockIdx.x * 4 + (threadIdx.x >> 6);
  const int l = threadIdx.x & 63;
  float m0 = mp[row], m1 = mp[49152 + row], m2 = mp[2 * 49152 + row], m3 = mp[3 * 49152 + row];
  float M = fmaxf(fmaxf(m0, m1), fmaxf(m2, m3));
  float w0 = __expf(m0 - M), w1 = __expf(m1 - M), w2 = __expf(m2 - M), w3 = __expf(m3 - M);
  float den = w0 * lp[row] + w1 * lp[49152 + row] + w2 * lp[2 * 49152 + row] + w3 * lp[3 * 49152 + row];
  float num = w0 * b2f(op[((size_t)0 * 49152 + row) * 64 + l])
            + w1 * b2f(op[((size_t)1 * 49152 + row) * 64 + l])
            + w2 * b2f(op[((size_t)2 * 49152 + row) * 64 + l])
            + w3 * b2f(op[((size_t)3 * 49152 + row) * 64 + l]);
  const int bh = row >> 11, qq = row & 2047;
  const int bb = bh / 12, hh = bh - bb * 12;
  y[((size_t)(bb * 2048 + qq)) * 768 + hh * 64 + l] = f2b(num / den);
}

// ---------------- proj combine + residual + LN2 fused ----------------
__global__ __launch_bounds__(256)
void proj_ln_k(const float* __restrict__ part, const float* __restrict__ bp,
               const float* __restrict__ xres, const float* __restrict__ g2,
               const float* __restrict__ bln2, float* __restrict__ xmid,
               unsigned short* __restrict__ h2) {
  const int row = blockIdx.x * 4 + (threadIdx.x >> 6);
  const int l = threadIdx.x & 63;
  float4 v[3];
  float s = 0.f, s2 = 0.f;
  #pragma unroll
  for (int j = 0; j < 3; ++j) {
    const int cc = l + j * 64;
    float4 a = ((const float4*)(xres + (size_t)row * 768))[cc];
    float4 bb = ((const float4*)bp)[cc];
    a.x += bb.x; a.y += bb.y; a.z += bb.z; a.w += bb.w;
    #pragma unroll
    for (int sp = 0; sp < 4; ++sp) {
      float4 pp = ((const float4*)(part + ((size_t)sp * 4096 + row) * 768))[cc];
      a.x += pp.x; a.y += pp.y; a.z += pp.z; a.w += pp.w;
    }
    v[j] = a;
    s += a.x + a.y + a.z + a.w;
    s2 += a.x * a.x + a.y * a.y + a.z * a.z + a.w * a.w;
  }
  #pragma unroll
  for (int d = 1; d < 64; d <<= 1) { s += __shfl_xor(s, d); s2 += __shfl_xor(s2, d); }
  const float mu = s * (1.0f / 768.0f);
  const float rstd = rsqrtf(s2 * (1.0f / 768.0f) - mu * mu + 1e-5f);
  #pragma unroll
  for (int j = 0; j < 3; ++j) {
    const int cc = l + j * 64;
    ((float4*)(xmid + (size_t)row * 768))[cc] = v[j];
    const int c0 = cc * 4;
    us4 ov;
    ov.x = f2b((v[j].x - mu) * rstd * g2[c0 + 0] + bln2[c0 + 0]);
    ov.y = f2b((v[j].y - mu) * rstd * g2[c0 + 1] + bln2[c0 + 1]);
    ov.z = f2b((v[j].z - mu) * rstd * g2[c0 + 2] + bln2[c0 + 2]);
    ov.w = f2b((v[j].w - mu) * rstd * g2[c0 + 3] + bln2[c0 + 3]);
    *(us4*)(h2 + (size_t)row * 768 + c0) = ov;
  }
}

// ---------------- MLP2 combine + bias + residual -> f32 out ----------------
__global__ void mlp2_comb_k(const float* __restrict__ part, const float* __restrict__ b2,
                            const float* __restrict__ xmid, float* __restrict__ out) {
  const int i = blockIdx.x * 256 + threadIdx.x;  // float4 index
  if (i >= 786432) return;
  const int c4 = i % 192;
  float4 a = ((const float4*)xmid)[i];
  float4 bb = ((const float4*)b2)[c4];
  a.x += bb.x; a.y += bb.y; a.z += bb.z; a.w += bb.w;
  #pragma unroll
  for (int sp = 0; sp < 4; ++sp) {
    float4 pp = ((const float4*)part)[(size_t)sp * 786432 + i];
    a.x += pp.x; a.y += pp.y; a.z += pp.z; a.w += pp.w;
  }
  ((float4*)out)[i] = a;
}

// ---------------- host ----------------
extern "C" void kernel_launch(void* const* d_in, const int* in_sizes, int n_in,
                              void* d_out, int out_size, void* d_ws, size_t ws_size,
                              hipStream_t stream) {
  const float* x    = (const float*)d_in[0];
  const int* condp  = (const int*)d_in[1];
  const int* pmask  = (const int*)d_in[2];
  const float* g1   = (const float*)d_in[3];
  const float* bln1 = (const float*)d_in[4];
  const float* g2   = (const float*)d_in[5];
  const float* bln2 = (const float*)d_in[6];
  const float* Wq   = (const float*)d_in[7];
  const float* bq   = (const float*)d_in[8];
  const float* Wk   = (const float*)d_in[9];
  const float* bk   = (const float*)d_in[10];
  const float* Wv   = (const float*)d_in[11];
  const float* bv   = (const float*)d_in[12];
  const float* Wp   = (const float*)d_in[13];
  const float* bp   = (const float*)d_in[14];
  const float* W1   = (const float*)d_in[15];
  const float* b1   = (const float*)d_in[16];
  const float* W2   = (const float*)d_in[17];
  const float* b2   = (const float*)d_in[18];

  char* p = (char*)d_ws;
  auto alloc = [&](size_t bytes) { char* r = p; p += (bytes + 255) & ~(size_t)255; return r; };
  unsigned short* Wqkv = (unsigned short*)alloc((size_t)2304 * 768 * 2);
  unsigned short* Wpb  = (unsigned short*)alloc((size_t)589824 * 2);
  unsigned short* W1b  = (unsigned short*)alloc((size_t)2359296 * 2);
  unsigned short* W2b  = (unsigned short*)alloc((size_t)2359296 * 2);
  unsigned short* hb   = (unsigned short*)alloc((size_t)4096 * 768 * 2);
  unsigned short* qkv  = (unsigned short*)alloc((size_t)4096 * 2304 * 2);
  unsigned short* vtb  = (unsigned short*)alloc((size_t)24 * 64 * 2048 * 2);
  float* xmid          = (float*)alloc((size_t)4096 * 768 * 4);
  unsigned short* h2b  = (unsigned short*)alloc((size_t)4096 * 768 * 2);
  float* abias         = (float*)alloc((size_t)2 * 2048 * 4);
  float* partial       = (float*)alloc((size_t)4 * 4096 * 768 * 4);   // 50.3 MB, multi-use
  // aliases (lifetimes disjoint):
  unsigned short* yb   = hb;                       // y after attn; hb dead after QKV gemm
  unsigned short* mlph = qkv;                      // spans qkv+vtb (25.17 MB), dead after attn
  unsigned short* opart = (unsigned short*)partial;                       // 25.17 MB
  float* mpart = (float*)((char*)partial + (size_t)4 * 49152 * 64 * 2);   // 786 KB
  float* lpart = mpart + 4 * 49152;                                       // 786 KB

  cvt_qkv_k<<<1728, 256, 0, stream>>>(Wq, Wk, Wv, Wqkv);
  cvt3_k<<<5184, 256, 0, stream>>>(Wp, W1, W2, Wpb, W1b, W2b);
  maskbias_k<<<2, 256, 0, stream>>>(pmask, condp, abias);
  ln_k<<<1024, 256, 0, stream>>>(x, g1, bln1, hb);
  gemm_k<0><<<576, 256, 0, stream>>>(hb, Wqkv, bq, bk, bv, qkv, vtb, 2304, 768, 18);
  attn_k<<<768, 512, 0, stream>>>(qkv, vtb, abias, opart, mpart, lpart);
  attn_comb_k<<<12288, 256, 0, stream>>>(opart, mpart, lpart, yb);
  gemm_pk<<<768, 256, 0, stream>>>(yb, Wpb, partial, 768, 768, 192, 6);
  proj_ln_k<<<1024, 256, 0, stream>>>(partial, bp, x, g2, bln2, xmid, h2b);
  gemm_k<2><<<768, 256, 0, stream>>>(h2b, W1b, b1, nullptr, nullptr, mlph, nullptr, 3072, 768, 24);
  gemm_pk<<<768, 256, 0, stream>>>(mlph, W2b, partial, 768, 3072, 768, 6);
  mlp2_comb_k<<<3072, 256, 0, stream>>>(partial, b2, xmid, (float*)d_out);
}

// Round 9
// 335.369 us; speedup vs baseline: 1.1848x; 1.0246x over previous
//
#include <hip/hip_runtime.h>
#include <hip/hip_bf16.h>
#include <math.h>

typedef short bf16x8 __attribute__((ext_vector_type(8)));
typedef float f32x4 __attribute__((ext_vector_type(4)));
typedef float f32x16 __attribute__((ext_vector_type(16)));
typedef unsigned short us4 __attribute__((ext_vector_type(4)));
typedef unsigned int uint2v __attribute__((ext_vector_type(2)));

#define MFMA16(a, b, c) __builtin_amdgcn_mfma_f32_16x16x32_bf16(a, b, c, 0, 0, 0)
#define MFMA32(a, b, c) __builtin_amdgcn_mfma_f32_32x32x16_bf16(a, b, c, 0, 0, 0)

#define KSCALE 0.18033688011112042f  /* 0.125 * log2(e): K pre-scale -> exp2 domain */
#define DEFER_THR 11.5f             /* = 8 * log2(e) */

__device__ __forceinline__ unsigned short f2b(float f) {
  unsigned int u = __builtin_bit_cast(unsigned int, f);
  u += 0x7fffu + ((u >> 16) & 1u);
  return (unsigned short)(u >> 16);
}

__device__ __forceinline__ float b2f(unsigned short u) {
  unsigned int x = ((unsigned int)u) << 16;
  return __builtin_bit_cast(float, x);
}

__device__ __forceinline__ unsigned int cvtpk(float lo, float hiv) {
  unsigned int r;
  asm("v_cvt_pk_bf16_f32 %0, %1, %2" : "=v"(r) : "v"(lo), "v"(hiv));
  return r;
}

__device__ __forceinline__ void gload16(const void* g, void* l) {
  __builtin_amdgcn_global_load_lds((const unsigned int*)g, (unsigned int*)l, 16, 0, 0);
}

// ---------------- merged weight conversion (1 launch) ----------------
__global__ void cvt_all_k(const float* __restrict__ wq, const float* __restrict__ wk,
                          const float* __restrict__ wv, const float* __restrict__ wp,
                          const float* __restrict__ w1, const float* __restrict__ w2,
                          unsigned short* __restrict__ Wqkv, unsigned short* __restrict__ Wpb,
                          unsigned short* __restrict__ W1b, unsigned short* __restrict__ W2b) {
  int i = blockIdx.x * 256 + threadIdx.x;  // float4 index
  const float* s; unsigned short* d; int j, o;
  if (i < 147456)            { s = wq; j = i;           d = Wqkv; o = i; }
  else if (i < 294912)       { s = wk; j = i - 147456;  d = Wqkv; o = i; }
  else if (i < 442368)       { s = wv; j = i - 294912;  d = Wqkv; o = i; }
  else if (i < 589824)       { s = wp; j = i - 442368;  d = Wpb;  o = j; }
  else if (i < 1179648)      { s = w1; j = i - 589824;  d = W1b;  o = j; }
  else if (i < 1769472)      { s = w2; j = i - 1179648; d = W2b;  o = j; }
  else return;
  float4 v = ((const float4*)s)[j];
  us4 ov; ov.x = f2b(v.x); ov.y = f2b(v.y); ov.z = f2b(v.z); ov.w = f2b(v.w);
  ((us4*)d)[o] = ov;
}

// ---------------- mask bias ----------------
__global__ void maskbias_k(const int* __restrict__ pm, const int* __restrict__ clp,
                           float* __restrict__ bias) {
  const int b = blockIdx.x, tid = threadIdx.x;
  int s = 0;
  for (int i = tid; i < 2048; i += 256) s += pm[b * 2048 + i];
  #pragma unroll
  for (int d = 1; d < 64; d <<= 1) s += __shfl_xor(s, d);
  __shared__ int red[4];
  if ((tid & 63) == 0) red[tid >> 6] = s;
  __syncthreads();
  const int n = 2048 - (red[0] + red[1] + red[2] + red[3]);
  const int cl = *clp;
  for (int t = tid; t < 2048; t += 256)
    bias[b * 2048 + t] = (t >= cl || t < n) ? 0.0f : -1e30f;
}

// ---------------- layernorm 1 (f32 in -> bf16 out), one wave per row ----------------
__global__ __launch_bounds__(256)
void ln_k(const float* __restrict__ x, const float* __restrict__ g,
          const float* __restrict__ be, unsigned short* __restrict__ out) {
  const int row = blockIdx.x * 4 + (threadIdx.x >> 6);
  const int l = threadIdx.x & 63;
  const float4* xr = (const float4*)(x + (size_t)row * 768);
  float4 v[3];
  float s = 0.f, s2 = 0.f;
  #pragma unroll
  for (int j = 0; j < 3; ++j) {
    v[j] = xr[l + j * 64];
    s += v[j].x + v[j].y + v[j].z + v[j].w;
    s2 += v[j].x * v[j].x + v[j].y * v[j].y + v[j].z * v[j].z + v[j].w * v[j].w;
  }
  #pragma unroll
  for (int d = 1; d < 64; d <<= 1) { s += __shfl_xor(s, d); s2 += __shfl_xor(s2, d); }
  const float mu = s * (1.0f / 768.0f);
  const float rstd = rsqrtf(s2 * (1.0f / 768.0f) - mu * mu + 1e-5f);
  #pragma unroll
  for (int j = 0; j < 3; ++j) {
    int c0 = (l + j * 64) * 4;
    us4 ov;
    ov.x = f2b((v[j].x - mu) * rstd * g[c0 + 0] + be[c0 + 0]);
    ov.y = f2b((v[j].y - mu) * rstd * g[c0 + 1] + be[c0 + 1]);
    ov.z = f2b((v[j].z - mu) * rstd * g[c0 + 2] + be[c0 + 2]);
    ov.w = f2b((v[j].w - mu) * rstd * g[c0 + 3] + be[c0 + 3]);
    *(us4*)(out + (size_t)row * 768 + c0) = ov;
  }
}

// ======== pipelined GEMM core: BK=64, double-buffered LDS, XOR-swizzled ========
#define GEMM_STAGE(buf, k0)                                                        \
  {                                                                                \
    _Pragma("unroll")                                                              \
    for (int i = 0; i < 4; ++i) {                                                  \
      int slot = i * 256 + tid;                                                    \
      int row = slot >> 3;                                                         \
      int c = (slot & 7) ^ (row & 7);                                              \
      gload16(A + (size_t)(m0 + row) * K + (k0) + c * 8,                           \
              (char*)At[buf] + slot * 16);                                         \
      gload16(W + (size_t)(n0 + row) * K + (k0) + c * 8,                           \
              (char*)Wt[buf] + slot * 16);                                         \
    }                                                                              \
  }

#define GEMM_COMPUTE(buf)                                                          \
  {                                                                                \
    const char* Ab = (const char*)At[buf];                                         \
    const char* Wb = (const char*)Wt[buf];                                         \
    _Pragma("unroll")                                                              \
    for (int kk = 0; kk < 2; ++kk) {                                               \
      bf16x8 af[4], bfr[4];                                                        \
      _Pragma("unroll")                                                            \
      for (int i = 0; i < 4; ++i) {                                                \
        int ar = wm * 64 + i * 16 + lr;                                            \
        af[i] = *(const bf16x8*)(Ab + ar * 128 + (((kk * 4 + lg) ^ (ar & 7)) << 4));\
        int br = wn * 64 + i * 16 + lr;                                            \
        bfr[i] = *(const bf16x8*)(Wb + br * 128 + (((kk * 4 + lg) ^ (br & 7)) << 4));\
      }                                                                            \
      _Pragma("unroll")                                                            \
      for (int mi = 0; mi < 4; ++mi)                                               \
        _Pragma("unroll")                                                          \
        for (int ni = 0; ni < 4; ++ni)                                             \
          acc[mi][ni] = MFMA16(af[mi], bfr[ni], acc[mi][ni]);                      \
    }                                                                              \
  }

// ---------------- GEMM: C[m][n] = sum_k A[m][k] * W[n][k] (+epilogue) ----------------
// MODE 0: QKV -> bf16 (K part pre-scaled by KSCALE), V-part transposed into out2
// MODE 2: bf16 out = gelu(acc + bias)
template<int MODE>
__global__ __launch_bounds__(256)
void gemm_k(const unsigned short* __restrict__ A, const unsigned short* __restrict__ W,
            const float* __restrict__ bias0, const float* __restrict__ bias1,
            const float* __restrict__ bias2, void* __restrict__ out,
            unsigned short* __restrict__ out2, int N, int K, int NN) {
  __shared__ __align__(16) unsigned short At[2][128 * 64];
  __shared__ __align__(16) unsigned short Wt[2][128 * 64];
  const int nwg8 = gridDim.x >> 3;
  const int swz = (blockIdx.x & 7) * nwg8 + (blockIdx.x >> 3);
  const int m0 = (swz & 31) * 128;
  const int n0 = ((swz >> 5) % NN) * 128;
  const int tid = threadIdx.x;
  const int w = tid >> 6, l = tid & 63;
  const int wm = w >> 1, wn = w & 1;
  const int lr = l & 15, lg = l >> 4;
  f32x4 acc[4][4] = {};

  const int nkt = K >> 6;
  GEMM_STAGE(0, 0);
  __syncthreads();
  for (int kt = 0; kt < nkt; ++kt) {
    if (kt + 1 < nkt) GEMM_STAGE((kt + 1) & 1, (kt + 1) << 6);
    GEMM_COMPUTE(kt & 1);
    __syncthreads();
  }

  #pragma unroll
  for (int mi = 0; mi < 4; ++mi) {
    #pragma unroll
    for (int ni = 0; ni < 4; ++ni) {
      #pragma unroll
      for (int r = 0; r < 4; ++r) {
        int row = m0 + wm * 64 + mi * 16 + lg * 4 + r;
        int col = n0 + wn * 64 + ni * 16 + lr;
        float v = acc[mi][ni][r];
        if (MODE == 0) {
          float bb = col < 768 ? bias0[col] : (col < 1536 ? bias1[col - 768] : bias2[col - 1536]);
          v += bb;
          if (col < 1536) {
            if (col >= 768) v *= KSCALE;
            ((unsigned short*)out)[(size_t)row * 2304 + col] = f2b(v);
          } else {
            int cc = col - 1536;
            int d = cc & 63, hh = cc >> 6;
            int b = row >> 11, t = row & 2047;
            out2[(((size_t)b * 12 + hh) * 64 + d) * 2048 + t] = f2b(v);
          }
        } else {
          v += bias0[col];
          v = 0.5f * v * (1.0f + erff(v * 0.70710678118f));
          ((unsigned short*)out)[(size_t)row * N + col] = f2b(v);
        }
      }
    }
  }
}

// ---------------- split-K GEMM -> f32 partials (same pipelined core) ----------------
__global__ __launch_bounds__(256)
void gemm_pk(const unsigned short* __restrict__ A, const unsigned short* __restrict__ W,
             float* __restrict__ part, int N, int K, int KS, int NN) {
  __shared__ __align__(16) unsigned short At[2][128 * 64];
  __shared__ __align__(16) unsigned short Wt[2][128 * 64];
  const int nwg8 = gridDim.x >> 3;
  const int swz = (blockIdx.x & 7) * nwg8 + (blockIdx.x >> 3);
  const int m0 = (swz & 31) * 128;
  const int rest = swz >> 5;
  const int n0 = (rest % NN) * 128;
  const int kb = (rest / NN) * KS;
  const int tid = threadIdx.x;
  const int w = tid >> 6, l = tid & 63;
  const int wm = w >> 1, wn = w & 1;
  const int lr = l & 15, lg = l >> 4;
  f32x4 acc[4][4] = {};

  const int nkt = KS >> 6;
  GEMM_STAGE(0, kb);
  __syncthreads();
  for (int kt = 0; kt < nkt; ++kt) {
    if (kt + 1 < nkt) GEMM_STAGE((kt + 1) & 1, kb + ((kt + 1) << 6));
    GEMM_COMPUTE(kt & 1);
    __syncthreads();
  }

  #pragma unroll
  for (int mi = 0; mi < 4; ++mi)
    #pragma unroll
    for (int ni = 0; ni < 4; ++ni)
      #pragma unroll
      for (int r = 0; r < 4; ++r) {
        int row = m0 + wm * 64 + mi * 16 + lg * 4 + r;
        int col = n0 + wn * 64 + ni * 16 + lr;
        part[((size_t)(rest / NN) * 4096 + row) * N + col] = acc[mi][ni][r];
      }
}

// ---------------- flash attention, 8 waves x 32 q-rows, 32x32 MFMA, swapped QK^T ----------
// Fragment-linear LDS: K/V stored as [frag][lane]*16B; wave w stages frag w.
// frag = ds*2 + khalf (K) / ks*2 + dhalf (V). All ds_reads: base + frag*1024 + l*16 (linear).
// Softmax in exp2 domain (K pre-scaled by KSCALE); defer-max (T13); permlane P-swap (T12).
__global__ __launch_bounds__(512, 4)
void attn_k(const unsigned short* __restrict__ qkv, const unsigned short* __restrict__ vt,
            const float* __restrict__ abias, unsigned short* __restrict__ opart,
            float* __restrict__ mpart, float* __restrict__ lpart) {
  __shared__ __align__(16) unsigned short Kt[8 * 512];
  __shared__ __align__(16) unsigned short Vt[8 * 512];
  __shared__ __align__(16) float absh[512];
  const int d0 = blockIdx.x;
  const int c = d0 & 7, t_ = d0 >> 3;
  const int G = (t_ >> 3) * 8 + c;      // 0..95 = bh*4 + split
  const int qt = t_ & 7;
  const int bh = G >> 2, split = G & 3;
  const int b = bh / 12, h = bh - b * 12;
  const int q0 = qt * 256;
  const int tb = split * 512;
  const int tid = threadIdx.x, w = tid >> 6, l = tid & 63;
  const int ql = l & 31, hi = l >> 5;
  const int q = q0 + w * 32 + ql;

  absh[tid] = abias[b * 2048 + tb + tid];

  bf16x8 qf[4];
  {
    const unsigned short* qrow = qkv + ((size_t)b * 2048 + q) * 2304 + h * 64 + hi * 8;
    #pragma unroll
    for (int ds = 0; ds < 4; ++ds) qf[ds] = *(const bf16x8*)(qrow + ds * 16);
  }

  f32x16 o0 = {}, o1 = {};
  float mrow = -1e30f, lrow = 0.f;

  // per-thread staging sources (wave w owns frag w on both K and V)
  const unsigned short* Kg = qkv + ((size_t)b * 2048 + tb + (w & 1) * 32 + ql) * 2304
                             + 768 + h * 64 + ((w >> 1) * 2 + hi) * 8;
  const unsigned short* Vg = vt + ((size_t)bh * 64 + (w & 1) * 32 + ql) * 2048
                             + tb + ((w >> 1) * 2 + hi) * 8;
  char* KtW = (char*)Kt + w * 1024;
  char* VtW = (char*)Vt + w * 1024;

  for (int tt = 0; tt < 8; ++tt) {
    gload16(Kg, KtW);
    gload16(Vg, VtW);
    Kg += 64 * 2304; Vg += 64;
    __syncthreads();

    // S^T = K·Q^T: lane holds S[q=ql][t = tt*64 + khalf*32 + (r&3)+8*(r>>2)+4*hi]
    f32x16 sa0 = {}, sa1 = {};
    #pragma unroll
    for (int ds = 0; ds < 4; ++ds) {
      bf16x8 kf0 = *(const bf16x8*)((const char*)Kt + (ds * 2 + 0) * 1024 + l * 16);
      bf16x8 kf1 = *(const bf16x8*)((const char*)Kt + (ds * 2 + 1) * 1024 + l * 16);
      sa0 = MFMA32(kf0, qf[ds], sa0);
      sa1 = MFMA32(kf1, qf[ds], sa1);
    }

    // + mask-bias, tile max (logits already in exp2 domain via K pre-scale)
    float mt = -1e30f;
    #pragma unroll
    for (int g = 0; g < 4; ++g) {
      float4 b0 = *(const float4*)&absh[tt * 64 + g * 8 + hi * 4];
      float4 b1 = *(const float4*)&absh[tt * 64 + 32 + g * 8 + hi * 4];
      float bb0[4] = {b0.x, b0.y, b0.z, b0.w};
      float bb1[4] = {b1.x, b1.y, b1.z, b1.w};
      #pragma unroll
      for (int r2 = 0; r2 < 4; ++r2) {
        float v0 = sa0[g * 4 + r2] + bb0[r2];
        float v1 = sa1[g * 4 + r2] + bb1[r2];
        sa0[g * 4 + r2] = v0; sa1[g * 4 + r2] = v1;
        mt = fmaxf(mt, fmaxf(v0, v1));
      }
    }
    mt = fmaxf(mt, __shfl_xor(mt, 32));

    // defer-max: only rescale when the running max grew by > DEFER_THR
    if (__any((int)(mt > mrow + DEFER_THR))) {
      const float mnew = fmaxf(mrow, mt);
      const float corr = exp2f(mrow - mnew);
      mrow = mnew;
      #pragma unroll
      for (int g = 0; g < 4; ++g)
        #pragma unroll
        for (int r2 = 0; r2 < 4; ++r2) {
          float cc2 = __shfl(corr, g * 8 + hi * 4 + r2);
          o0[g * 4 + r2] *= cc2;
          o1[g * 4 + r2] *= cc2;
        }
      lrow *= corr;
    }

    float rs = 0.f;
    auto half_pv = [&](const f32x16& sv, int ksb) {
      unsigned int u[8];
      #pragma unroll
      for (int g = 0; g < 4; ++g) {
        float e0 = exp2f(sv[g * 4 + 0] - mrow);
        float e1 = exp2f(sv[g * 4 + 1] - mrow);
        float e2 = exp2f(sv[g * 4 + 2] - mrow);
        float e3 = exp2f(sv[g * 4 + 3] - mrow);
        rs += (e0 + e1) + (e2 + e3);
        u[g * 2]     = cvtpk(e0, e1);
        u[g * 2 + 1] = cvtpk(e2, e3);
      }
      #pragma unroll
      for (int kh = 0; kh < 2; ++kh) {
        unsigned int a0 = u[kh * 4 + 0], a1 = u[kh * 4 + 1];
        unsigned int c0 = u[kh * 4 + 2], c1 = u[kh * 4 + 3];
        // permlane32_swap(vdst=c, src=a): c'[0:31]=a[32:63], a'[32:63]=c[0:31].
        // Post: a = {own u0 | partner u2}, c = {partner u0 | own u2}
        //  == verified shfl mapping {hi? xc : a, hi? c : xa}.
        uint2v r0 = __builtin_amdgcn_permlane32_swap(c0, a0, false, false);
        c0 = r0.x; a0 = r0.y;
        uint2v r1 = __builtin_amdgcn_permlane32_swap(c1, a1, false, false);
        c1 = r1.x; a1 = r1.y;
        uint4 pk; pk.x = a0; pk.y = a1; pk.z = c0; pk.w = c1;
        bf16x8 pa = __builtin_bit_cast(bf16x8, pk);
        const int ks = ksb + kh;
        bf16x8 vf0 = *(const bf16x8*)((const char*)Vt + (ks * 2 + 0) * 1024 + l * 16);
        o0 = MFMA32(pa, vf0, o0);
        bf16x8 vf1 = *(const bf16x8*)((const char*)Vt + (ks * 2 + 1) * 1024 + l * 16);
        o1 = MFMA32(pa, vf1, o1);
      }
    };
    half_pv(sa0, 0);
    half_pv(sa1, 2);

    rs += __shfl_xor(rs, 32);
    lrow += rs;
    __syncthreads();
  }

  const size_t orow0 = (size_t)split * 49152 + (size_t)bh * 2048 + q0 + w * 32;
  if (hi == 0) { mpart[orow0 + ql] = mrow; lpart[orow0 + ql] = lrow; }
  #pragma unroll
  for (int g = 0; g < 4; ++g)
    #pragma unroll
    for (int r2 = 0; r2 < 4; ++r2) {
      int oq = r2 + g * 8 + hi * 4;
      opart[(orow0 + oq) * 64 + ql]      = f2b(o0[g * 4 + r2]);
      opart[(orow0 + oq) * 64 + 32 + ql] = f2b(o1[g * 4 + r2]);
    }
}

// ---------------- attention split combine (exp2 domain) ----------------
__global__ __launch_bounds__(256)
void attn_comb_k(const unsigned short* __restrict__ op, const float* __restrict__ mp,
                 const float* __restrict__ lp, unsigned short* __restrict__ y) {
  const int row = blockIdx.x * 4 + (threadIdx.x >> 6);
  const int l = threadIdx.x & 63;
  float m0 = mp[row], m1 = mp[49152 + row], m2 = mp[2 * 49152 + row], m3 = mp[3 * 49152 + row];
  float M = fmaxf(fmaxf(m0, m1), fmaxf(m2, m3));
  float w0 = exp2f(m0 - M), w1 = exp2f(m1 - M), w2 = exp2f(m2 - M), w3 = exp2f(m3 - M);
  float den = w0 * lp[row] + w1 * lp[49152 + row] + w2 * lp[2 * 49152 + row] + w3 * lp[3 * 49152 + row];
  float num = w0 * b2f(op[((size_t)0 * 49152 + row) * 64 + l])
            + w1 * b2f(op[((size_t)1 * 49152 + row) * 64 + l])
            + w2 * b2f(op[((size_t)2 * 49152 + row) * 64 + l])
            + w3 * b2f(op[((size_t)3 * 49152 + row) * 64 + l]);
  const int bh = row >> 11, qq = row & 2047;
  const int bb = bh / 12, hh = bh - bb * 12;
  y[((size_t)(bb * 2048 + qq)) * 768 + hh * 64 + l] = f2b(num / den);
}

// ---------------- proj combine + residual + LN2 fused ----------------
__global__ __launch_bounds__(256)
void proj_ln_k(const float* __restrict__ part, const float* __restrict__ bp,
               const float* __restrict__ xres, const float* __restrict__ g2,
               const float* __restrict__ bln2, float* __restrict__ xmid,
               unsigned short* __restrict__ h2) {
  const int row = blockIdx.x * 4 + (threadIdx.x >> 6);
  const int l = threadIdx.x & 63;
  float4 v[3];
  float s = 0.f, s2 = 0.f;
  #pragma unroll
  for (int j = 0; j < 3; ++j) {
    const int cc = l + j * 64;
    float4 a = ((const float4*)(xres + (size_t)row * 768))[cc];
    float4 bb = ((const float4*)bp)[cc];
    a.x += bb.x; a.y += bb.y; a.z += bb.z; a.w += bb.w;
    #pragma unroll
    for (int sp = 0; sp < 4; ++sp) {
      float4 pp = ((const float4*)(part + ((size_t)sp * 4096 + row) * 768))[cc];
      a.x += pp.x; a.y += pp.y; a.z += pp.z; a.w += pp.w;
    }
    v[j] = a;
    s += a.x + a.y + a.z + a.w;
    s2 += a.x * a.x + a.y * a.y + a.z * a.z + a.w * a.w;
  }
  #pragma unroll
  for (int d = 1; d < 64; d <<= 1) { s += __shfl_xor(s, d); s2 += __shfl_xor(s2, d); }
  const float mu = s * (1.0f / 768.0f);
  const float rstd = rsqrtf(s2 * (1.0f / 768.0f) - mu * mu + 1e-5f);
  #pragma unroll
  for (int j = 0; j < 3; ++j) {
    const int cc = l + j * 64;
    ((float4*)(xmid + (size_t)row * 768))[cc] = v[j];
    const int c0 = cc * 4;
    us4 ov;
    ov.x = f2b((v[j].x - mu) * rstd * g2[c0 + 0] + bln2[c0 + 0]);
    ov.y = f2b((v[j].y - mu) * rstd * g2[c0 + 1] + bln2[c0 + 1]);
    ov.z = f2b((v[j].z - mu) * rstd * g2[c0 + 2] + bln2[c0 + 2]);
    ov.w = f2b((v[j].w - mu) * rstd * g2[c0 + 3] + bln2[c0 + 3]);
    *(us4*)(h2 + (size_t)row * 768 + c0) = ov;
  }
}

// ---------------- MLP2 combine + bias + residual -> f32 out ----------------
__global__ void mlp2_comb_k(const float* __restrict__ part, const float* __restrict__ b2,
                            const float* __restrict__ xmid, float* __restrict__ out) {
  const int i = blockIdx.x * 256 + threadIdx.x;  // float4 index
  if (i >= 786432) return;
  const int c4 = i % 192;
  float4 a = ((const float4*)xmid)[i];
  float4 bb = ((const float4*)b2)[c4];
  a.x += bb.x; a.y += bb.y; a.z += bb.z; a.w += bb.w;
  #pragma unroll
  for (int sp = 0; sp < 4; ++sp) {
    float4 pp = ((const float4*)part)[(size_t)sp * 786432 + i];
    a.x += pp.x; a.y += pp.y; a.z += pp.z; a.w += pp.w;
  }
  ((float4*)out)[i] = a;
}

// ---------------- host ----------------
extern "C" void kernel_launch(void* const* d_in, const int* in_sizes, int n_in,
                              void* d_out, int out_size, void* d_ws, size_t ws_size,
                              hipStream_t stream) {
  const float* x    = (const float*)d_in[0];
  const int* condp  = (const int*)d_in[1];
  const int* pmask  = (const int*)d_in[2];
  const float* g1   = (const float*)d_in[3];
  const float* bln1 = (const float*)d_in[4];
  const float* g2   = (const float*)d_in[5];
  const float* bln2 = (const float*)d_in[6];
  const float* Wq   = (const float*)d_in[7];
  const float* bq   = (const float*)d_in[8];
  const float* Wk   = (const float*)d_in[9];
  const float* bk   = (const float*)d_in[10];
  const float* Wv   = (const float*)d_in[11];
  const float* bv   = (const float*)d_in[12];
  const float* Wp   = (const float*)d_in[13];
  const float* bp   = (const float*)d_in[14];
  const float* W1   = (const float*)d_in[15];
  const float* b1   = (const float*)d_in[16];
  const float* W2   = (const float*)d_in[17];
  const float* b2   = (const float*)d_in[18];

  char* p = (char*)d_ws;
  auto alloc = [&](size_t bytes) { char* r = p; p += (bytes + 255) & ~(size_t)255; return r; };
  unsigned short* Wqkv = (unsigned short*)alloc((size_t)2304 * 768 * 2);
  unsigned short* Wpb  = (unsigned short*)alloc((size_t)589824 * 2);
  unsigned short* W1b  = (unsigned short*)alloc((size_t)2359296 * 2);
  unsigned short* W2b  = (unsigned short*)alloc((size_t)2359296 * 2);
  unsigned short* hb   = (unsigned short*)alloc((size_t)4096 * 768 * 2);
  unsigned short* qkv  = (unsigned short*)alloc((size_t)4096 * 2304 * 2);
  unsigned short* vtb  = (unsigned short*)alloc((size_t)24 * 64 * 2048 * 2);
  float* xmid          = (float*)alloc((size_t)4096 * 768 * 4);
  unsigned short* h2b  = (unsigned short*)alloc((size_t)4096 * 768 * 2);
  float* abias         = (float*)alloc((size_t)2 * 2048 * 4);
  float* partial       = (float*)alloc((size_t)4 * 4096 * 768 * 4);   // 50.3 MB, multi-use
  // aliases (lifetimes disjoint):
  unsigned short* yb   = hb;                       // y after attn; hb dead after QKV gemm
  unsigned short* mlph = qkv;                      // spans qkv+vtb, dead after attn
  unsigned short* opart = (unsigned short*)partial;                       // 25.17 MB
  float* mpart = (float*)((char*)partial + (size_t)4 * 49152 * 64 * 2);   // 786 KB
  float* lpart = mpart + 4 * 49152;                                       // 786 KB

  cvt_all_k<<<6912, 256, 0, stream>>>(Wq, Wk, Wv, Wp, W1, W2, Wqkv, Wpb, W1b, W2b);
  maskbias_k<<<2, 256, 0, stream>>>(pmask, condp, abias);
  ln_k<<<1024, 256, 0, stream>>>(x, g1, bln1, hb);
  gemm_k<0><<<576, 256, 0, stream>>>(hb, Wqkv, bq, bk, bv, qkv, vtb, 2304, 768, 18);
  attn_k<<<768, 512, 0, stream>>>(qkv, vtb, abias, opart, mpart, lpart);
  attn_comb_k<<<12288, 256, 0, stream>>>(opart, mpart, lpart, yb);
  gemm_pk<<<768, 256, 0, stream>>>(yb, Wpb, partial, 768, 768, 192, 6);
  proj_ln_k<<<1024, 256, 0, stream>>>(partial, bp, x, g2, bln2, xmid, h2b);
  gemm_k<2><<<768, 256, 0, stream>>>(h2b, W1b, b1, nullptr, nullptr, mlph, nullptr, 3072, 768, 24);
  gemm_pk<<<768, 256, 0, stream>>>(mlph, W2b, partial, 768, 3072, 768, 6);
  mlp2_comb_k<<<3072, 256, 0, stream>>>(partial, b2, xmid, (float*)d_out);
}